// Round 3
// baseline (417.739 us; speedup 1.0000x reference)
//
#include <hip/hip_runtime.h>
#include <hip/hip_bf16.h>

// ---- problem constants ----
#define B_SZ 4
#define S_SZ 2048
#define DM   1024
#define NH   8
#define DK   128
#define DC   32
#define DHR  32
#define DQK  160            // DK + DHR
#define T_TOK (B_SZ * S_SZ) // 8192
#define SCALE 0.07905694150420949f // 1/sqrt(160)
#define C2LOG 0.11405506439f       // SCALE * log2(e): softmax in exp2 domain

typedef unsigned int uint;
typedef unsigned short ushort;
typedef __attribute__((ext_vector_type(8))) short short8;
typedef __attribute__((ext_vector_type(4))) float floatx4;
typedef __attribute__((ext_vector_type(16))) float floatx16;
typedef __attribute__((ext_vector_type(4))) uint uintx4;

__device__ __forceinline__ ushort f2bf(float f) {
    uint u = __float_as_uint(f);
    uint r = u + 0x7fffu + ((u >> 16) & 1u);
    return (ushort)(r >> 16);
}
__device__ __forceinline__ uint packbf(float x, float y) {
    return (uint)f2bf(x) | ((uint)f2bf(y) << 16);
}

// async global->LDS, 16B per lane; lds dest = wave-uniform base + lane*16
__device__ __forceinline__ void glds16(const ushort* g, ushort* l) {
    __builtin_amdgcn_global_load_lds(
        (const __attribute__((address_space(1))) uint*)g,
        (__attribute__((address_space(3))) uint*)l, 16, 0, 0);
}

// ============================================================
// Kernel 1: c_q, c_kv, k_r  = h_t @ {W_DQ, W_DKV, W_KR} + bias
// (unchanged)
// ============================================================
__global__ __launch_bounds__(256) void latent_kernel(
    const float* __restrict__ h_t,
    const float* __restrict__ W_DQ, const float* __restrict__ b_DQ,
    const float* __restrict__ W_DKV, const float* __restrict__ b_DKV,
    const float* __restrict__ W_KR, const float* __restrict__ b_KR,
    float* __restrict__ c_q, float* __restrict__ c_kv, float* __restrict__ k_r)
{
    __shared__ __align__(16) float hs[32 * 33];
    __shared__ __align__(16) float wq[32 * 32];
    __shared__ __align__(16) float wkv[32 * 32];
    __shared__ __align__(16) float wkr[32 * 32];

    const int tid = threadIdx.x;
    const int t0 = blockIdx.x * 32;
    const int t = tid & 31;
    const int g = tid >> 5;

    float acc_q[4] = {0.f, 0.f, 0.f, 0.f};
    float acc_kv[4] = {0.f, 0.f, 0.f, 0.f};
    float acc_kr[4] = {0.f, 0.f, 0.f, 0.f};

    const int lr = tid >> 3;
    const int lc = (tid & 7) * 4;

    for (int k0 = 0; k0 < DM; k0 += 32) {
        __syncthreads();
        {
            float4 v = *(const float4*)&h_t[(size_t)(t0 + lr) * DM + k0 + lc];
            hs[lr * 33 + lc + 0] = v.x;
            hs[lr * 33 + lc + 1] = v.y;
            hs[lr * 33 + lc + 2] = v.z;
            hs[lr * 33 + lc + 3] = v.w;
        }
        {
            float4 a = *(const float4*)&W_DQ[(size_t)(k0 + lr) * 32 + lc];
            wq[lr * 32 + lc + 0] = a.x; wq[lr * 32 + lc + 1] = a.y;
            wq[lr * 32 + lc + 2] = a.z; wq[lr * 32 + lc + 3] = a.w;
            float4 b = *(const float4*)&W_DKV[(size_t)(k0 + lr) * 32 + lc];
            wkv[lr * 32 + lc + 0] = b.x; wkv[lr * 32 + lc + 1] = b.y;
            wkv[lr * 32 + lc + 2] = b.z; wkv[lr * 32 + lc + 3] = b.w;
            float4 c = *(const float4*)&W_KR[(size_t)(k0 + lr) * 32 + lc];
            wkr[lr * 32 + lc + 0] = c.x; wkr[lr * 32 + lc + 1] = c.y;
            wkr[lr * 32 + lc + 2] = c.z; wkr[lr * 32 + lc + 3] = c.w;
        }
        __syncthreads();
        #pragma unroll 8
        for (int kk = 0; kk < 32; ++kk) {
            float a = hs[t * 33 + kk];
            #pragma unroll
            for (int cc = 0; cc < 4; ++cc) {
                int c = g * 4 + cc;
                acc_q[cc] += a * wq[kk * 32 + c];
                acc_kv[cc] += a * wkv[kk * 32 + c];
                acc_kr[cc] += a * wkr[kk * 32 + c];
            }
        }
    }
    #pragma unroll
    for (int cc = 0; cc < 4; ++cc) {
        int c = g * 4 + cc;
        int idx = (t0 + t) * 32 + c;
        c_q[idx] = acc_q[cc] + b_DQ[c];
        c_kv[idx] = acc_kv[cc] + b_DKV[c];
        k_r[idx] = acc_kr[cc] + b_KR[c];
    }
}

// ============================================================
// Kernel 2: build q, k, v (bf16) in [bh][s][d] layout. (unchanged)
// ============================================================
__global__ __launch_bounds__(256) void build_qkv_kernel(
    const float* __restrict__ c_q, const float* __restrict__ c_kv,
    const float* __restrict__ k_r,
    const float* __restrict__ W_UQ, const float* __restrict__ b_UQ,
    const float* __restrict__ W_UK, const float* __restrict__ b_UK,
    const float* __restrict__ W_UV, const float* __restrict__ b_UV,
    const float* __restrict__ W_QR, const float* __restrict__ b_QR,
    ushort* __restrict__ q_ws, ushort* __restrict__ k_ws, ushort* __restrict__ v_ws)
{
    __shared__ __align__(16) float cb[16 * 96];
    const int tid = threadIdx.x;
    const int t0 = blockIdx.x * 16;

    for (int i = tid; i < 512; i += 256) {
        int tt = i >> 5, c = i & 31;
        cb[tt * 96 + c] = c_q[(t0 + tt) * 32 + c];
        cb[tt * 96 + 32 + c] = c_kv[(t0 + tt) * 32 + c];
        cb[tt * 96 + 64 + c] = k_r[(t0 + tt) * 32 + c];
    }
    __syncthreads();

    for (int i = 0; i < 14; ++i) {
        int e = i * 256 + tid;
        int h = e / 448;
        int r = e - h * 448;

        float acc[16];
        if (r >= 288 && r < 320) {
            #pragma unroll
            for (int tt = 0; tt < 16; ++tt) acc[tt] = cb[tt * 96 + 64 + (r - 288)];
        } else {
            const float* W; const float* bias; int stride, col, coff;
            if (r < 128)      { W = W_UQ; stride = 1024; col = h * 128 + r;        coff = 0;  bias = b_UQ; }
            else if (r < 160) { W = W_QR; stride = 256;  col = h * 32 + (r - 128); coff = 0;  bias = b_QR; }
            else if (r < 288) { W = W_UK; stride = 1024; col = h * 128 + (r - 160);coff = 32; bias = b_UK; }
            else              { W = W_UV; stride = 1024; col = h * 128 + (r - 320);coff = 32; bias = b_UV; }
            float bv = bias[col];
            #pragma unroll
            for (int tt = 0; tt < 16; ++tt) acc[tt] = bv;
            for (int kk = 0; kk < 32; ++kk) {
                float w = W[kk * stride + col];
                #pragma unroll
                for (int tt = 0; tt < 16; ++tt) acc[tt] += cb[tt * 96 + coff + kk] * w;
            }
        }
        #pragma unroll
        for (int tt = 0; tt < 16; ++tt) {
            int tok = t0 + tt;
            int b = tok >> 11, s = tok & 2047;
            int bh = b * NH + h;
            ushort val = f2bf(acc[tt]);
            if (r < 160)      q_ws[((size_t)bh * S_SZ + s) * DQK + r] = val;
            else if (r < 320) k_ws[((size_t)bh * S_SZ + s) * DQK + (r - 160)] = val;
            else              v_ws[((size_t)bh * S_SZ + s) * DK + (r - 320)] = val;
        }
    }
}

// ============================================================
// Kernel 3: 32x32x16-MFMA flash attention, 256 threads (4 waves).
// Each wave owns 32 Q rows -> 128 rows/block; 1D grid of 512 blocks with
// XCD de-swizzle: virt = (wg&7)*64 + (wg>>3), so each XCD's 64 blocks
// cover 4 consecutive bh -> K/V stays L2-resident per XCD (T1).
// Sc^T = K.Q^T (A=K from LDS, B=Q in regs); O^T = V^T.P^T.
// 32x32 C/D layout (verified): col=lane&31, row=(r&3)+8*(r>>2)+4*(lane>>5).
// PV k-mapping = the one lanes already hold (sigma staged into V):
// sigma(k)=16*(k>>4)+8*((k>>2)&1)+4*((k>>3)&1)+(k&3); pf = in-lane
// cvt_pk of consecutive sc pairs -> scalar uints -> bit_cast (NO union,
// NO scratch: round-2's 190 MB WRITE_SIZE was union spill traffic).
// Softmax: exp2 domain, always-rescale, __shfl_xor(.,32) reductions.
// T14: next tile's K/V global loads issued under compute. LDS 39936 B.
// ============================================================
__global__ __launch_bounds__(256, 2) void attn_mfma_kernel(
    const ushort* __restrict__ q_ws, const ushort* __restrict__ k_ws,
    const ushort* __restrict__ v_ws, ushort* __restrict__ o_ws)
{
    __shared__ __align__(16) ushort SH[64 * 168 + 128 * 72]; // 39936 B
    ushort* const Ks = SH;             // [key 64][d 160], stride 168
    ushort* const Vt = SH + 64 * 168;  // [d 128][key-slot 64], stride 72

    const int tid  = threadIdx.x;
    const int wave = tid >> 6;   // 0..3
    const int lane = tid & 63;
    const int l32  = lane & 31;
    const int hi   = lane >> 5;
    const int hi8  = hi * 8;

    // XCD-aware de-swizzle (8 XCDs, 512 blocks -> bijective)
    const int wg = blockIdx.x;
    const int virt = (wg & 7) * 64 + (wg >> 3);
    const int bh = virt >> 4;
    const int b = bh >> 3, h = bh & 7;
    const int s0 = (virt & 15) * 128;
    const int qrow_base = s0 + wave * 32;

    // Q fragments: B[k = st*16 + hi*8 + j][qcol = l32], 10 k-steps of 16
    short8 qf[10];
    {
        const ushort* qp = q_ws + ((size_t)bh * S_SZ + qrow_base + l32) * DQK + hi8;
        #pragma unroll
        for (int st = 0; st < 10; ++st)
            qf[st] = *(const short8*)&qp[st * 16];
    }

    floatx16 oa[4];  // O^T: col=qrow(l32), row d = vt*32 + (r&3)+8*(r>>2)+4*hi
    #pragma unroll
    for (int vt = 0; vt < 4; ++vt)
        oa[vt] = (floatx16){0.f,0.f,0.f,0.f,0.f,0.f,0.f,0.f,
                            0.f,0.f,0.f,0.f,0.f,0.f,0.f,0.f};

    float m2 = -3.0e38f;   // running max in exp2-scaled domain
    float l_run = 0.f;

    const ushort* kbase = k_ws + (size_t)bh * S_SZ * DQK;
    const ushort* vbase = v_ws + (size_t)bh * S_SZ * DK;

    // T14 prefetch registers
    uint4 kpre[5];
    uint vpa[8], vpb[8];
    {
        const uint4* kg = (const uint4*)kbase;
        #pragma unroll
        for (int j = 0; j < 5; ++j) kpre[j] = kg[tid + j * 256];
        const uint* vg = (const uint*)vbase;
        #pragma unroll
        for (int c = 0; c < 8; ++c) {
            int kp = wave * 8 + c;
            vpa[c] = vg[(2 * kp) * 64 + lane];
            vpb[c] = vg[(2 * kp + 1) * 64 + lane];
        }
    }

    for (int kt = 0; kt < S_SZ / 64; ++kt) {
        __syncthreads(); // all waves done reading prior tile

        // ---- write prefetched K tile (natural order, contiguous copy)
        #pragma unroll
        for (int j = 0; j < 5; ++j) {
            int i = tid + j * 256;
            int row = i / 20, seg = i - row * 20;
            *(uint4*)&Ks[row * 168 + seg * 8] = kpre[j];
        }
        // ---- write prefetched V transposed, with sigma key-slot grouping:
        // wave's 8 uint cols get data {lo0,lo1,lo4,lo5 | lo2,lo3,lo6,lo7}
        {
            uint* vt32 = (uint*)Vt;
            uint lo[8], hh[8];
            #pragma unroll
            for (int c = 0; c < 8; ++c) {
                lo[c] = (vpa[c] & 0xffffu) | (vpb[c] << 16);
                hh[c] = (vpa[c] >> 16) | (vpb[c] & 0xffff0000u);
            }
            *(uint4*)&vt32[(2 * lane) * 36 + wave * 8]     = make_uint4(lo[0], lo[1], lo[4], lo[5]);
            *(uint4*)&vt32[(2 * lane) * 36 + wave * 8 + 4] = make_uint4(lo[2], lo[3], lo[6], lo[7]);
            *(uint4*)&vt32[(2 * lane + 1) * 36 + wave * 8]     = make_uint4(hh[0], hh[1], hh[4], hh[5]);
            *(uint4*)&vt32[(2 * lane + 1) * 36 + wave * 8 + 4] = make_uint4(hh[2], hh[3], hh[6], hh[7]);
        }
        __syncthreads();

        // ---- issue next tile's global loads; latency hides under compute
        if (kt + 1 < S_SZ / 64) {
            const uint4* kg = (const uint4*)(kbase + (size_t)(kt + 1) * 64 * DQK);
            #pragma unroll
            for (int j = 0; j < 5; ++j) kpre[j] = kg[tid + j * 256];
            const uint* vg = (const uint*)(vbase + (size_t)(kt + 1) * 64 * DK);
            #pragma unroll
            for (int c = 0; c < 8; ++c) {
                int kp = wave * 8 + c;
                vpa[c] = vg[(2 * kp) * 64 + lane];
                vpb[c] = vg[(2 * kp + 1) * 64 + lane];
            }
        }

        // ---- Sc^T = K.Q^T : D[m=key][n=qrow], 2 key-blocks of 32
        floatx16 sc[2];
        __builtin_amdgcn_s_setprio(1);
        #pragma unroll
        for (int kb = 0; kb < 2; ++kb) {
            floatx16 acc = (floatx16){0.f,0.f,0.f,0.f,0.f,0.f,0.f,0.f,
                                      0.f,0.f,0.f,0.f,0.f,0.f,0.f,0.f};
            const ushort* krow = &Ks[(size_t)(kb * 32 + l32) * 168 + hi8];
            #pragma unroll
            for (int st = 0; st < 10; ++st) {
                short8 kf = *(const short8*)&krow[st * 16];
                acc = __builtin_amdgcn_mfma_f32_32x32x16_bf16(kf, qf[st], acc, 0, 0, 0);
            }
            sc[kb] = acc;
        }
        __builtin_amdgcn_s_setprio(0);

        // ---- online softmax, exp2 domain, always-rescale (proven flow)
        {
            float tmax = -3.0e38f;
            #pragma unroll
            for (int kb = 0; kb < 2; ++kb)
                #pragma unroll
                for (int r = 0; r < 16; ++r)
                    tmax = fmaxf(tmax, sc[kb][r]);
            tmax *= C2LOG;
            tmax = fmaxf(tmax, __shfl_xor(tmax, 32));

            float mnew = fmaxf(m2, tmax);
            float al = __builtin_amdgcn_exp2f(m2 - mnew);
            m2 = mnew;

            float rsum = 0.f;
            #pragma unroll
            for (int kb = 0; kb < 2; ++kb)
                #pragma unroll
                for (int r = 0; r < 16; ++r) {
                    float p = __builtin_amdgcn_exp2f(__builtin_fmaf(sc[kb][r], C2LOG, -mnew));
                    sc[kb][r] = p;
                    rsum += p;
                }
            rsum += __shfl_xor(rsum, 32);
            l_run = l_run * al + rsum;

            #pragma unroll
            for (int vt = 0; vt < 4; ++vt)
                #pragma unroll
                for (int r = 0; r < 16; ++r)
                    oa[vt][r] *= al;
        }

        // ---- O^T += V^T . P^T ; pf = in-lane cvt_pk of consecutive sc pairs
        // (scalar asm outs + bit_cast: pure SSA, no union, no scratch)
        __builtin_amdgcn_s_setprio(1);
        #pragma unroll
        for (int kb = 0; kb < 2; ++kb) {
            #pragma unroll
            for (int s = 0; s < 2; ++s) {
                uint w0, w1, w2, w3;
                asm("v_cvt_pk_bf16_f32 %0, %1, %2" : "=v"(w0)
                    : "v"(sc[kb][8 * s + 0]), "v"(sc[kb][8 * s + 1]));
                asm("v_cvt_pk_bf16_f32 %0, %1, %2" : "=v"(w1)
                    : "v"(sc[kb][8 * s + 2]), "v"(sc[kb][8 * s + 3]));
                asm("v_cvt_pk_bf16_f32 %0, %1, %2" : "=v"(w2)
                    : "v"(sc[kb][8 * s + 4]), "v"(sc[kb][8 * s + 5]));
                asm("v_cvt_pk_bf16_f32 %0, %1, %2" : "=v"(w3)
                    : "v"(sc[kb][8 * s + 6]), "v"(sc[kb][8 * s + 7]));
                short8 pv = __builtin_bit_cast(short8, (uintx4){w0, w1, w2, w3});
                #pragma unroll
                for (int vt = 0; vt < 4; ++vt) {
                    short8 vf = *(const short8*)&Vt[(size_t)(vt * 32 + l32) * 72
                                                    + kb * 32 + s * 16 + hi8];
                    oa[vt] = __builtin_amdgcn_mfma_f32_32x32x16_bf16(vf, pv, oa[vt], 0, 0, 0);
                }
            }
        }
        __builtin_amdgcn_s_setprio(0);
    }

    // ---- epilogue: transpose O^T -> O through reused LDS, coalesced store
    __syncthreads(); // everyone done with Ks/Vt
    ushort* ot = SH + wave * (32 * 136); // per-wave 32 rows x 136 us
    uint* ot32 = (uint*)ot;
    {
        float inv = 1.0f / l_run;
        #pragma unroll
        for (int vt = 0; vt < 4; ++vt)
            #pragma unroll
            for (int g = 0; g < 4; ++g) {
                int base = l32 * 68 + vt * 16 + g * 4 + hi * 2;
                ot32[base]     = packbf(oa[vt][g * 4 + 0] * inv, oa[vt][g * 4 + 1] * inv);
                ot32[base + 1] = packbf(oa[vt][g * 4 + 2] * inv, oa[vt][g * 4 + 3] * inv);
            }
    }
    // same-wave LDS ordering: no barrier needed
    #pragma unroll
    for (int pass = 0; pass < 8; ++pass) {
        int row_in = pass * 4 + (lane >> 4);
        int col8 = (lane & 15) * 8;
        uint4 v = *(const uint4*)&ot[row_in * 136 + col8];
        int srow = qrow_base + row_in;
        *(uint4*)(o_ws + (((size_t)b * S_SZ + srow) * NH + h) * DK + col8) = v;
    }
}

// ============================================================
// Kernel 4a: W_O [1024 k][1024 n] fp32 -> W_O^T bf16 [n][k] (unchanged)
// ============================================================
__global__ __launch_bounds__(256) void transpose_wo_kernel(
    const float* __restrict__ W_O, ushort* __restrict__ wot)
{
    __shared__ float t[32][33];
    const int tx = threadIdx.x & 31, ty = threadIdx.x >> 5;
    const int n0 = blockIdx.x * 32, k0 = blockIdx.y * 32;
    #pragma unroll
    for (int j = 0; j < 32; j += 8)
        t[ty + j][tx] = W_O[(size_t)(k0 + ty + j) * DM + n0 + tx];
    __syncthreads();
    #pragma unroll
    for (int j = 0; j < 32; j += 8)
        wot[(size_t)(n0 + ty + j) * DM + k0 + tx] = f2bf(t[tx][ty + j]);
}

// ============================================================
// Kernel 4b: out = o_ws @ W_O + b_O via MFMA (unchanged)
// ============================================================
__global__ __launch_bounds__(256) void out_gemm_mfma_kernel(
    const ushort* __restrict__ A,    // o_ws [8192][1024] bf16
    const ushort* __restrict__ BT,   // wot  [1024 n][1024 k] bf16
    const float* __restrict__ b_O, float* __restrict__ out)
{
    __shared__ __align__(16) ushort As[128 * 32];
    __shared__ __align__(16) ushort Bs[128 * 32];

    const int tid = threadIdx.x;
    const int wave = tid >> 6;
    const int lane = tid & 63;
    const int quad = lane >> 4;
    const int l16 = lane & 15;
    const int wr = wave >> 1, wc = wave & 1;

    const int n0 = blockIdx.x * 128;
    const int m0 = blockIdx.y * 128;

    const int lrow = lane >> 2;
    const int lseg = (lane & 3) * 8;

    floatx4 acc[4][4];
    #pragma unroll
    for (int mt = 0; mt < 4; ++mt)
        #pragma unroll
        for (int nt = 0; nt < 4; ++nt)
            acc[mt][nt] = (floatx4){0.f, 0.f, 0.f, 0.f};

    for (int k0 = 0; k0 < DM; k0 += 32) {
        __syncthreads();
        {
            const ushort* g0 = A + (size_t)(m0 + wave * 32 + lrow) * DM + k0 + lseg;
            glds16(g0, &As[(wave * 32) * 32]);
            const ushort* g1 = A + (size_t)(m0 + wave * 32 + 16 + lrow) * DM + k0 + lseg;
            glds16(g1, &As[(wave * 32 + 16) * 32]);
        }
        {
            const ushort* g0 = BT + (size_t)(n0 + wave * 32 + lrow) * DM + k0 + lseg;
            glds16(g0, &Bs[(wave * 32) * 32]);
            const ushort* g1 = BT + (size_t)(n0 + wave * 32 + 16 + lrow) * DM + k0 + lseg;
            glds16(g1, &Bs[(wave * 32 + 16) * 32]);
        }
        __syncthreads();

        short8 af[4], bf[4];
        #pragma unroll
        for (int mt = 0; mt < 4; ++mt)
            af[mt] = *(const short8*)&As[(wr * 64 + mt * 16 + l16) * 32 + quad * 8];
        #pragma unroll
        for (int nt = 0; nt < 4; ++nt)
            bf[nt] = *(const short8*)&Bs[(wc * 64 + nt * 16 + l16) * 32 + quad * 8];
        #pragma unroll
        for (int mt = 0; mt < 4; ++mt)
            #pragma unroll
            for (int nt = 0; nt < 4; ++nt)
                acc[mt][nt] = __builtin_amdgcn_mfma_f32_16x16x32_bf16(af[mt], bf[nt], acc[mt][nt], 0, 0, 0);
    }

    float bo[4];
    #pragma unroll
    for (int nt = 0; nt < 4; ++nt) bo[nt] = b_O[n0 + wc * 64 + nt * 16 + l16];

    #pragma unroll
    for (int mt = 0; mt < 4; ++mt) {
        #pragma unroll
        for (int r = 0; r < 4; ++r) {
            int row = m0 + wr * 64 + mt * 16 + quad * 4 + r;
            float* orow = out + (size_t)row * DM + n0 + wc * 64;
            #pragma unroll
            for (int nt = 0; nt < 4; ++nt)
                orow[nt * 16 + l16] = acc[mt][nt][r] + bo[nt];
        }
    }
}

// ============================================================
extern "C" void kernel_launch(void* const* d_in, const int* in_sizes, int n_in,
                              void* d_out, int out_size, void* d_ws, size_t ws_size,
                              hipStream_t stream) {
    (void)in_sizes; (void)n_in; (void)out_size; (void)ws_size;

    const float* h_t   = (const float*)d_in[0];
    const float* W_DQ  = (const float*)d_in[1];
    const float* b_DQ  = (const float*)d_in[2];
    const float* W_UQ  = (const float*)d_in[3];
    const float* b_UQ  = (const float*)d_in[4];
    const float* W_DKV = (const float*)d_in[5];
    const float* b_DKV = (const float*)d_in[6];
    const float* W_UK  = (const float*)d_in[7];
    const float* b_UK  = (const float*)d_in[8];
    const float* W_UV  = (const float*)d_in[9];
    const float* b_UV  = (const float*)d_in[10];
    const float* W_QR  = (const float*)d_in[11];
    const float* b_QR  = (const float*)d_in[12];
    const float* W_KR  = (const float*)d_in[13];
    const float* b_KR  = (const float*)d_in[14];
    const float* W_O   = (const float*)d_in[15];
    const float* b_O   = (const float*)d_in[16];

    float* c_q  = (float*)d_ws;
    float* c_kv = c_q + T_TOK * DC;
    float* k_r  = c_kv + T_TOK * DC;
    ushort* q_ws = (ushort*)(k_r + T_TOK * DC);
    ushort* k_ws = q_ws + (size_t)B_SZ * NH * S_SZ * DQK;
    ushort* v_ws = k_ws + (size_t)B_SZ * NH * S_SZ * DQK;
    ushort* o_ws = v_ws + (size_t)B_SZ * NH * S_SZ * DK;
    ushort* wot  = o_ws + (size_t)T_TOK * DM;

    float* out = (float*)d_out;

    latent_kernel<<<T_TOK / 32, 256, 0, stream>>>(
        h_t, W_DQ, b_DQ, W_DKV, b_DKV, W_KR, b_KR, c_q, c_kv, k_r);

    transpose_wo_kernel<<<dim3(32, 32), 256, 0, stream>>>(W_O, wot);

    build_qkv_kernel<<<T_TOK / 16, 256, 0, stream>>>(
        c_q, c_kv, k_r, W_UQ, b_UQ, W_UK, b_UK, W_UV, b_UV, W_QR, b_QR,
        q_ws, k_ws, v_ws);

    attn_mfma_kernel<<<512, 256, 0, stream>>>(
        q_ws, k_ws, v_ws, o_ws);

    out_gemm_mfma_kernel<<<dim3(DM / 128, T_TOK / 128), 256, 0, stream>>>(
        o_ws, wot, b_O, out);
}

// Round 4
// 370.588 us; speedup vs baseline: 1.1272x; 1.1272x over previous
//
#include <hip/hip_runtime.h>
#include <hip/hip_bf16.h>

// ---- problem constants ----
#define B_SZ 4
#define S_SZ 2048
#define DM   1024
#define NH   8
#define DK   128
#define DC   32
#define DHR  32
#define DQK  160            // DK + DHR
#define T_TOK (B_SZ * S_SZ) // 8192
#define SCALE 0.07905694150420949f // 1/sqrt(160)
#define C2LOG 0.11405506439f       // SCALE * log2(e): softmax in exp2 domain
#define NT    (S_SZ / 64)   // 32 key tiles

typedef unsigned int uint;
typedef unsigned short ushort;
typedef __attribute__((ext_vector_type(8))) short short8;
typedef __attribute__((ext_vector_type(4))) float floatx4;
typedef __attribute__((ext_vector_type(16))) float floatx16;
typedef __attribute__((ext_vector_type(4))) uint uintx4;

__device__ __forceinline__ ushort f2bf(float f) {
    uint u = __float_as_uint(f);
    uint r = u + 0x7fffu + ((u >> 16) & 1u);
    return (ushort)(r >> 16);
}
__device__ __forceinline__ uint packbf(float x, float y) {
    return (uint)f2bf(x) | ((uint)f2bf(y) << 16);
}

// async global->LDS, 16B per lane; lds dest = wave-uniform base + lane*16
__device__ __forceinline__ void glds16(const ushort* g, ushort* l) {
    __builtin_amdgcn_global_load_lds(
        (const __attribute__((address_space(1))) uint*)g,
        (__attribute__((address_space(3))) uint*)l, 16, 0, 0);
}

// ============================================================
// Kernel 1: c_q, c_kv, k_r  = h_t @ {W_DQ, W_DKV, W_KR} + bias
// (unchanged)
// ============================================================
__global__ __launch_bounds__(256) void latent_kernel(
    const float* __restrict__ h_t,
    const float* __restrict__ W_DQ, const float* __restrict__ b_DQ,
    const float* __restrict__ W_DKV, const float* __restrict__ b_DKV,
    const float* __restrict__ W_KR, const float* __restrict__ b_KR,
    float* __restrict__ c_q, float* __restrict__ c_kv, float* __restrict__ k_r)
{
    __shared__ __align__(16) float hs[32 * 33];
    __shared__ __align__(16) float wq[32 * 32];
    __shared__ __align__(16) float wkv[32 * 32];
    __shared__ __align__(16) float wkr[32 * 32];

    const int tid = threadIdx.x;
    const int t0 = blockIdx.x * 32;
    const int t = tid & 31;
    const int g = tid >> 5;

    float acc_q[4] = {0.f, 0.f, 0.f, 0.f};
    float acc_kv[4] = {0.f, 0.f, 0.f, 0.f};
    float acc_kr[4] = {0.f, 0.f, 0.f, 0.f};

    const int lr = tid >> 3;
    const int lc = (tid & 7) * 4;

    for (int k0 = 0; k0 < DM; k0 += 32) {
        __syncthreads();
        {
            float4 v = *(const float4*)&h_t[(size_t)(t0 + lr) * DM + k0 + lc];
            hs[lr * 33 + lc + 0] = v.x;
            hs[lr * 33 + lc + 1] = v.y;
            hs[lr * 33 + lc + 2] = v.z;
            hs[lr * 33 + lc + 3] = v.w;
        }
        {
            float4 a = *(const float4*)&W_DQ[(size_t)(k0 + lr) * 32 + lc];
            wq[lr * 32 + lc + 0] = a.x; wq[lr * 32 + lc + 1] = a.y;
            wq[lr * 32 + lc + 2] = a.z; wq[lr * 32 + lc + 3] = a.w;
            float4 b = *(const float4*)&W_DKV[(size_t)(k0 + lr) * 32 + lc];
            wkv[lr * 32 + lc + 0] = b.x; wkv[lr * 32 + lc + 1] = b.y;
            wkv[lr * 32 + lc + 2] = b.z; wkv[lr * 32 + lc + 3] = b.w;
            float4 c = *(const float4*)&W_KR[(size_t)(k0 + lr) * 32 + lc];
            wkr[lr * 32 + lc + 0] = c.x; wkr[lr * 32 + lc + 1] = c.y;
            wkr[lr * 32 + lc + 2] = c.z; wkr[lr * 32 + lc + 3] = c.w;
        }
        __syncthreads();
        #pragma unroll 8
        for (int kk = 0; kk < 32; ++kk) {
            float a = hs[t * 33 + kk];
            #pragma unroll
            for (int cc = 0; cc < 4; ++cc) {
                int c = g * 4 + cc;
                acc_q[cc] += a * wq[kk * 32 + c];
                acc_kv[cc] += a * wkv[kk * 32 + c];
                acc_kr[cc] += a * wkr[kk * 32 + c];
            }
        }
    }
    #pragma unroll
    for (int cc = 0; cc < 4; ++cc) {
        int c = g * 4 + cc;
        int idx = (t0 + t) * 32 + c;
        c_q[idx] = acc_q[cc] + b_DQ[c];
        c_kv[idx] = acc_kv[cc] + b_DKV[c];
        k_r[idx] = acc_kr[cc] + b_KR[c];
    }
}

// ============================================================
// Kernel 2: build q, k, v (bf16) in [bh][s][d] layout. (unchanged)
// ============================================================
__global__ __launch_bounds__(256) void build_qkv_kernel(
    const float* __restrict__ c_q, const float* __restrict__ c_kv,
    const float* __restrict__ k_r,
    const float* __restrict__ W_UQ, const float* __restrict__ b_UQ,
    const float* __restrict__ W_UK, const float* __restrict__ b_UK,
    const float* __restrict__ W_UV, const float* __restrict__ b_UV,
    const float* __restrict__ W_QR, const float* __restrict__ b_QR,
    ushort* __restrict__ q_ws, ushort* __restrict__ k_ws, ushort* __restrict__ v_ws)
{
    __shared__ __align__(16) float cb[16 * 96];
    const int tid = threadIdx.x;
    const int t0 = blockIdx.x * 16;

    for (int i = tid; i < 512; i += 256) {
        int tt = i >> 5, c = i & 31;
        cb[tt * 96 + c] = c_q[(t0 + tt) * 32 + c];
        cb[tt * 96 + 32 + c] = c_kv[(t0 + tt) * 32 + c];
        cb[tt * 96 + 64 + c] = k_r[(t0 + tt) * 32 + c];
    }
    __syncthreads();

    for (int i = 0; i < 14; ++i) {
        int e = i * 256 + tid;
        int h = e / 448;
        int r = e - h * 448;

        float acc[16];
        if (r >= 288 && r < 320) {
            #pragma unroll
            for (int tt = 0; tt < 16; ++tt) acc[tt] = cb[tt * 96 + 64 + (r - 288)];
        } else {
            const float* W; const float* bias; int stride, col, coff;
            if (r < 128)      { W = W_UQ; stride = 1024; col = h * 128 + r;        coff = 0;  bias = b_UQ; }
            else if (r < 160) { W = W_QR; stride = 256;  col = h * 32 + (r - 128); coff = 0;  bias = b_QR; }
            else if (r < 288) { W = W_UK; stride = 1024; col = h * 128 + (r - 160);coff = 32; bias = b_UK; }
            else              { W = W_UV; stride = 1024; col = h * 128 + (r - 320);coff = 32; bias = b_UV; }
            float bv = bias[col];
            #pragma unroll
            for (int tt = 0; tt < 16; ++tt) acc[tt] = bv;
            for (int kk = 0; kk < 32; ++kk) {
                float w = W[kk * stride + col];
                #pragma unroll
                for (int tt = 0; tt < 16; ++tt) acc[tt] += cb[tt * 96 + coff + kk] * w;
            }
        }
        #pragma unroll
        for (int tt = 0; tt < 16; ++tt) {
            int tok = t0 + tt;
            int b = tok >> 11, s = tok & 2047;
            int bh = b * NH + h;
            ushort val = f2bf(acc[tt]);
            if (r < 160)      q_ws[((size_t)bh * S_SZ + s) * DQK + r] = val;
            else if (r < 320) k_ws[((size_t)bh * S_SZ + s) * DQK + (r - 160)] = val;
            else              v_ws[((size_t)bh * S_SZ + s) * DK + (r - 320)] = val;
        }
    }
}

// ============================================================
// Kernel 3: 32x32x16-MFMA flash attention, 256 threads (4 waves),
// DOUBLE-BUFFERED K/V in LDS -> ONE barrier per tile; stage overlaps
// compute (T3-lite). K is staged via global_load_lds direct (linear
// dest, stride 160us rows) with XOR bank-swizzle applied on the READ
// side and the INVERSE applied to the per-lane GLOBAL source offsets
// (both-sides rule, m173/m201): phys = la ^ ((row&7)<<4), bijective.
// V stays reg-transposed (16 dword loads + 4 ds_write_b128), written
// LATE in the tile so HBM/L2 latency hides under QK+softmax+PV.
// XCD de-swizzle grid (T1). Defer-rescale THR=8 (T13).
// Sc^T = K.Q^T ; O^T = V^T.P^T with sigma-staged V (round-1 trick).
// LDS: K 2x20480B + V 2x18432B = 77824 B, 2 blocks/CU.
// ============================================================
__global__ __launch_bounds__(256, 2) void attn_mfma_kernel(
    const ushort* __restrict__ q_ws, const ushort* __restrict__ k_ws,
    const ushort* __restrict__ v_ws, ushort* __restrict__ o_ws)
{
    __shared__ __align__(16) ushort SH[38912]; // 77824 B
    // us offsets: Ks buf0 @0, buf1 @10240; Vt buf0 @20480, buf1 @29696
    const int tid  = threadIdx.x;
    const int wave = tid >> 6;   // 0..3
    const int lane = tid & 63;
    const int l32  = lane & 31;
    const int hi   = lane >> 5;
    const int hi8  = hi * 8;

    // XCD-aware de-swizzle (8 XCDs, 512 blocks -> bijective)
    const int wg = blockIdx.x;
    const int virt = (wg & 7) * 64 + (wg >> 3);
    const int bh = virt >> 4;
    const int b = bh >> 3, h = bh & 7;
    const int s0 = (virt & 15) * 128;
    const int qrow_base = s0 + wave * 32;

    const ushort* kbase = k_ws + (size_t)bh * S_SZ * DQK;
    const ushort* vbase = v_ws + (size_t)bh * S_SZ * DK;

    // ---- K staging source offsets (inverse of read-side XOR swizzle).
    // dest byte d in [0,20480) holds global byte la with
    // la ^ ((floor(la/320)&7)<<4) == d ; exactly one candidate row passes.
    int ksrc[5];
    #pragma unroll
    for (int j = 0; j < 5; ++j) {
        int d = (tid + j * 256) * 16;
        int r0 = d / 320;
        int la = d;
        #pragma unroll
        for (int dr = -1; dr <= 1; ++dr) {
            int r = r0 + dr;
            int cand = d ^ ((r & 7) << 4);
            if (cand / 320 == r) la = cand;
        }
        ksrc[j] = la;
    }
    // per-wave-uniform LDS dest base (HW adds lane*16B)
    const int kdst_us = (wave * 64) * 8; // + j*256*8, + buf*10240

    // Q fragments: B[k = st*16 + hi*8 + j][qcol = l32], 10 k-steps of 16
    short8 qf[10];
    {
        const ushort* qp = q_ws + ((size_t)bh * S_SZ + qrow_base + l32) * DQK + hi8;
        #pragma unroll
        for (int st = 0; st < 10; ++st)
            qf[st] = *(const short8*)&qp[st * 16];
    }

    floatx16 oa[4];  // O^T: col=qrow(l32), row d = vt*32 + (r&3)+8*(r>>2)+4*hi
    #pragma unroll
    for (int vt = 0; vt < 4; ++vt)
        oa[vt] = (floatx16){0.f,0.f,0.f,0.f,0.f,0.f,0.f,0.f,
                            0.f,0.f,0.f,0.f,0.f,0.f,0.f,0.f};

    float m2 = -3.0e38f;   // running max in exp2-scaled domain
    float l_run = 0.f;

    // ---- prologue: stage tile 0 into buf 0
    {
        #pragma unroll
        for (int j = 0; j < 5; ++j)
            glds16((const ushort*)((const char*)kbase + ksrc[j]),
                   SH + kdst_us + j * 2048);
        uint vpa[8], vpb[8];
        const uint* vg = (const uint*)vbase;
        #pragma unroll
        for (int c = 0; c < 8; ++c) {
            int kp = wave * 8 + c;
            vpa[c] = vg[(2 * kp) * 64 + lane];
            vpb[c] = vg[(2 * kp + 1) * 64 + lane];
        }
        uint* vt32 = (uint*)(SH + 20480);
        uint lo[8], hh[8];
        #pragma unroll
        for (int c = 0; c < 8; ++c) {
            lo[c] = (vpa[c] & 0xffffu) | (vpb[c] << 16);
            hh[c] = (vpa[c] >> 16) | (vpb[c] & 0xffff0000u);
        }
        *(uint4*)&vt32[(2 * lane) * 36 + wave * 8]     = make_uint4(lo[0], lo[1], lo[4], lo[5]);
        *(uint4*)&vt32[(2 * lane) * 36 + wave * 8 + 4] = make_uint4(lo[2], lo[3], lo[6], lo[7]);
        *(uint4*)&vt32[(2 * lane + 1) * 36 + wave * 8]     = make_uint4(hh[0], hh[1], hh[4], hh[5]);
        *(uint4*)&vt32[(2 * lane + 1) * 36 + wave * 8 + 4] = make_uint4(hh[2], hh[3], hh[6], hh[7]);
    }

    const int kmask = (l32 & 7) << 4;

    for (int kt = 0; kt < NT; ++kt) {
        const int cur = kt & 1, nxt = cur ^ 1;
        __syncthreads(); // drains prev gl_lds + ds_writes; buf[cur] ready

        // ---- issue next tile's K DMA + V loads (latency hides under compute)
        uint vpa[8], vpb[8];
        if (kt + 1 < NT) {
            const char* kg = (const char*)(kbase + (size_t)(kt + 1) * 64 * DQK);
            #pragma unroll
            for (int j = 0; j < 5; ++j)
                glds16((const ushort*)(kg + ksrc[j]),
                       SH + nxt * 10240 + kdst_us + j * 2048);
            const uint* vg = (const uint*)(vbase + (size_t)(kt + 1) * 64 * DK);
            #pragma unroll
            for (int c = 0; c < 8; ++c) {
                int kp = wave * 8 + c;
                vpa[c] = vg[(2 * kp) * 64 + lane];
                vpb[c] = vg[(2 * kp + 1) * 64 + lane];
            }
        }

        // ---- Sc^T = K.Q^T : D[m=key][n=qrow], 2 key-blocks of 32
        const char* kbufc = (const char*)(SH + cur * 10240);
        floatx16 sc[2];
        __builtin_amdgcn_s_setprio(1);
        #pragma unroll
        for (int kb = 0; kb < 2; ++kb) {
            floatx16 acc = (floatx16){0.f,0.f,0.f,0.f,0.f,0.f,0.f,0.f,
                                      0.f,0.f,0.f,0.f,0.f,0.f,0.f,0.f};
            const int row_la = (kb * 32 + l32) * 320 + hi * 16;
            #pragma unroll
            for (int st = 0; st < 10; ++st) {
                short8 kf = *(const short8*)(kbufc + ((row_la + st * 32) ^ kmask));
                acc = __builtin_amdgcn_mfma_f32_32x32x16_bf16(kf, qf[st], acc, 0, 0, 0);
            }
            sc[kb] = acc;
        }
        __builtin_amdgcn_s_setprio(0);

        // ---- online softmax, exp2 domain, defer-rescale (T13, THR=8)
        {
            float tmax = -3.0e38f;
            #pragma unroll
            for (int kb = 0; kb < 2; ++kb)
                #pragma unroll
                for (int r = 0; r < 16; ++r)
                    tmax = fmaxf(tmax, sc[kb][r]);
            tmax *= C2LOG;
            tmax = fmaxf(tmax, __shfl_xor(tmax, 32));

            if (__any(tmax > m2 + 8.0f)) {
                float mnew = fmaxf(m2, tmax);
                float al = __builtin_amdgcn_exp2f(m2 - mnew);
                m2 = mnew;
                l_run *= al;
                #pragma unroll
                for (int vt = 0; vt < 4; ++vt)
                    #pragma unroll
                    for (int r = 0; r < 16; ++r)
                        oa[vt][r] *= al;
            }

            float rsum = 0.f;
            #pragma unroll
            for (int kb = 0; kb < 2; ++kb)
                #pragma unroll
                for (int r = 0; r < 16; ++r) {
                    float p = __builtin_amdgcn_exp2f(__builtin_fmaf(sc[kb][r], C2LOG, -m2));
                    sc[kb][r] = p;
                    rsum += p;
                }
            rsum += __shfl_xor(rsum, 32);
            l_run += rsum;
        }

        // ---- O^T += V^T . P^T ; pf = in-lane cvt_pk of consecutive sc pairs
        const ushort* vtc = SH + 20480 + cur * 9216;
        __builtin_amdgcn_s_setprio(1);
        #pragma unroll
        for (int kb = 0; kb < 2; ++kb) {
            #pragma unroll
            for (int s = 0; s < 2; ++s) {
                uint w0, w1, w2, w3;
                asm("v_cvt_pk_bf16_f32 %0, %1, %2" : "=v"(w0)
                    : "v"(sc[kb][8 * s + 0]), "v"(sc[kb][8 * s + 1]));
                asm("v_cvt_pk_bf16_f32 %0, %1, %2" : "=v"(w1)
                    : "v"(sc[kb][8 * s + 2]), "v"(sc[kb][8 * s + 3]));
                asm("v_cvt_pk_bf16_f32 %0, %1, %2" : "=v"(w2)
                    : "v"(sc[kb][8 * s + 4]), "v"(sc[kb][8 * s + 5]));
                asm("v_cvt_pk_bf16_f32 %0, %1, %2" : "=v"(w3)
                    : "v"(sc[kb][8 * s + 6]), "v"(sc[kb][8 * s + 7]));
                short8 pv = __builtin_bit_cast(short8, (uintx4){w0, w1, w2, w3});
                #pragma unroll
                for (int vt = 0; vt < 4; ++vt) {
                    short8 vf = *(const short8*)&vtc[(size_t)(vt * 32 + l32) * 72
                                                     + kb * 32 + s * 16 + hi8];
                    oa[vt] = __builtin_amdgcn_mfma_f32_32x32x16_bf16(vf, pv, oa[vt], 0, 0, 0);
                }
            }
        }
        __builtin_amdgcn_s_setprio(0);

        // ---- late V stage into buf[nxt] (loads issued at tile top are done)
        if (kt + 1 < NT) {
            uint* vt32 = (uint*)(SH + 20480 + nxt * 9216);
            uint lo[8], hh[8];
            #pragma unroll
            for (int c = 0; c < 8; ++c) {
                lo[c] = (vpa[c] & 0xffffu) | (vpb[c] << 16);
                hh[c] = (vpa[c] >> 16) | (vpb[c] & 0xffff0000u);
            }
            *(uint4*)&vt32[(2 * lane) * 36 + wave * 8]     = make_uint4(lo[0], lo[1], lo[4], lo[5]);
            *(uint4*)&vt32[(2 * lane) * 36 + wave * 8 + 4] = make_uint4(lo[2], lo[3], lo[6], lo[7]);
            *(uint4*)&vt32[(2 * lane + 1) * 36 + wave * 8]     = make_uint4(hh[0], hh[1], hh[4], hh[5]);
            *(uint4*)&vt32[(2 * lane + 1) * 36 + wave * 8 + 4] = make_uint4(hh[2], hh[3], hh[6], hh[7]);
        }
    }

    // ---- epilogue: transpose O^T -> O through reused LDS, coalesced store
    __syncthreads(); // everyone done with K/V buffers
    ushort* ot = SH + wave * (32 * 136); // per-wave 32 rows x 136 us
    uint* ot32 = (uint*)ot;
    {
        float inv = 1.0f / l_run;
        #pragma unroll
        for (int vt = 0; vt < 4; ++vt)
            #pragma unroll
            for (int g = 0; g < 4; ++g) {
                int base = l32 * 68 + vt * 16 + g * 4 + hi * 2;
                ot32[base]     = packbf(oa[vt][g * 4 + 0] * inv, oa[vt][g * 4 + 1] * inv);
                ot32[base + 1] = packbf(oa[vt][g * 4 + 2] * inv, oa[vt][g * 4 + 3] * inv);
            }
    }
    // same-wave LDS ordering: no barrier needed
    #pragma unroll
    for (int pass = 0; pass < 8; ++pass) {
        int row_in = pass * 4 + (lane >> 4);
        int col8 = (lane & 15) * 8;
        uint4 v = *(const uint4*)&ot[row_in * 136 + col8];
        int srow = qrow_base + row_in;
        *(uint4*)(o_ws + (((size_t)b * S_SZ + srow) * NH + h) * DK + col8) = v;
    }
}

// ============================================================
// Kernel 4a: W_O [1024 k][1024 n] fp32 -> W_O^T bf16 [n][k] (unchanged)
// ============================================================
__global__ __launch_bounds__(256) void transpose_wo_kernel(
    const float* __restrict__ W_O, ushort* __restrict__ wot)
{
    __shared__ float t[32][33];
    const int tx = threadIdx.x & 31, ty = threadIdx.x >> 5;
    const int n0 = blockIdx.x * 32, k0 = blockIdx.y * 32;
    #pragma unroll
    for (int j = 0; j < 32; j += 8)
        t[ty + j][tx] = W_O[(size_t)(k0 + ty + j) * DM + n0 + tx];
    __syncthreads();
    #pragma unroll
    for (int j = 0; j < 32; j += 8)
        wot[(size_t)(n0 + ty + j) * DM + k0 + tx] = f2bf(t[tx][ty + j]);
}

// ============================================================
// Kernel 4b: out = o_ws @ W_O + b_O via MFMA (unchanged)
// ============================================================
__global__ __launch_bounds__(256) void out_gemm_mfma_kernel(
    const ushort* __restrict__ A,    // o_ws [8192][1024] bf16
    const ushort* __restrict__ BT,   // wot  [1024 n][1024 k] bf16
    const float* __restrict__ b_O, float* __restrict__ out)
{
    __shared__ __align__(16) ushort As[128 * 32];
    __shared__ __align__(16) ushort Bs[128 * 32];

    const int tid = threadIdx.x;
    const int wave = tid >> 6;
    const int lane = tid & 63;
    const int quad = lane >> 4;
    const int l16 = lane & 15;
    const int wr = wave >> 1, wc = wave & 1;

    const int n0 = blockIdx.x * 128;
    const int m0 = blockIdx.y * 128;

    const int lrow = lane >> 2;
    const int lseg = (lane & 3) * 8;

    floatx4 acc[4][4];
    #pragma unroll
    for (int mt = 0; mt < 4; ++mt)
        #pragma unroll
        for (int nt = 0; nt < 4; ++nt)
            acc[mt][nt] = (floatx4){0.f, 0.f, 0.f, 0.f};

    for (int k0 = 0; k0 < DM; k0 += 32) {
        __syncthreads();
        {
            const ushort* g0 = A + (size_t)(m0 + wave * 32 + lrow) * DM + k0 + lseg;
            glds16(g0, &As[(wave * 32) * 32]);
            const ushort* g1 = A + (size_t)(m0 + wave * 32 + 16 + lrow) * DM + k0 + lseg;
            glds16(g1, &As[(wave * 32 + 16) * 32]);
        }
        {
            const ushort* g0 = BT + (size_t)(n0 + wave * 32 + lrow) * DM + k0 + lseg;
            glds16(g0, &Bs[(wave * 32) * 32]);
            const ushort* g1 = BT + (size_t)(n0 + wave * 32 + 16 + lrow) * DM + k0 + lseg;
            glds16(g1, &Bs[(wave * 32 + 16) * 32]);
        }
        __syncthreads();

        short8 af[4], bf[4];
        #pragma unroll
        for (int mt = 0; mt < 4; ++mt)
            af[mt] = *(const short8*)&As[(wr * 64 + mt * 16 + l16) * 32 + quad * 8];
        #pragma unroll
        for (int nt = 0; nt < 4; ++nt)
            bf[nt] = *(const short8*)&Bs[(wc * 64 + nt * 16 + l16) * 32 + quad * 8];
        #pragma unroll
        for (int mt = 0; mt < 4; ++mt)
            #pragma unroll
            for (int nt = 0; nt < 4; ++nt)
                acc[mt][nt] = __builtin_amdgcn_mfma_f32_16x16x32_bf16(af[mt], bf[nt], acc[mt][nt], 0, 0, 0);
    }

    float bo[4];
    #pragma unroll
    for (int nt = 0; nt < 4; ++nt) bo[nt] = b_O[n0 + wc * 64 + nt * 16 + l16];

    #pragma unroll
    for (int mt = 0; mt < 4; ++mt) {
        #pragma unroll
        for (int r = 0; r < 4; ++r) {
            int row = m0 + wr * 64 + mt * 16 + quad * 4 + r;
            float* orow = out + (size_t)row * DM + n0 + wc * 64;
            #pragma unroll
            for (int nt = 0; nt < 4; ++nt)
                orow[nt * 16 + l16] = acc[mt][nt][r] + bo[nt];
        }
    }
}

// ============================================================
extern "C" void kernel_launch(void* const* d_in, const int* in_sizes, int n_in,
                              void* d_out, int out_size, void* d_ws, size_t ws_size,
                              hipStream_t stream) {
    (void)in_sizes; (void)n_in; (void)out_size; (void)ws_size;

    const float* h_t   = (const float*)d_in[0];
    const float* W_DQ  = (const float*)d_in[1];
    const float* b_DQ  = (const float*)d_in[2];
    const float* W_UQ  = (const float*)d_in[3];
    const float* b_UQ  = (const float*)d_in[4];
    const float* W_DKV = (const float*)d_in[5];
    const float* b_DKV = (const float*)d_in[6];
    const float* W_UK  = (const float*)d_in[7];
    const float* b_UK  = (const float*)d_in[8];
    const float* W_UV  = (const float*)d_in[9];
    const float* b_UV  = (const float*)d_in[10];
    const float* W_QR  = (const float*)d_in[11];
    const float* b_QR  = (const float*)d_in[12];
    const float* W_KR  = (const float*)d_in[13];
    const float* b_KR  = (const float*)d_in[14];
    const float* W_O   = (const float*)d_in[15];
    const float* b_O   = (const float*)d_in[16];

    float* c_q  = (float*)d_ws;
    float* c_kv = c_q + T_TOK * DC;
    float* k_r  = c_kv + T_TOK * DC;
    ushort* q_ws = (ushort*)(k_r + T_TOK * DC);
    ushort* k_ws = q_ws + (size_t)B_SZ * NH * S_SZ * DQK;
    ushort* v_ws = k_ws + (size_t)B_SZ * NH * S_SZ * DQK;
    ushort* o_ws = v_ws + (size_t)B_SZ * NH * S_SZ * DK;
    ushort* wot  = o_ws + (size_t)T_TOK * DM;

    float* out = (float*)d_out;

    latent_kernel<<<T_TOK / 32, 256, 0, stream>>>(
        h_t, W_DQ, b_DQ, W_DKV, b_DKV, W_KR, b_KR, c_q, c_kv, k_r);

    transpose_wo_kernel<<<dim3(32, 32), 256, 0, stream>>>(W_O, wot);

    build_qkv_kernel<<<T_TOK / 16, 256, 0, stream>>>(
        c_q, c_kv, k_r, W_UQ, b_UQ, W_UK, b_UK, W_UV, b_UV, W_QR, b_QR,
        q_ws, k_ws, v_ws);

    attn_mfma_kernel<<<512, 256, 0, stream>>>(
        q_ws, k_ws, v_ws, o_ws);

    out_gemm_mfma_kernel<<<dim3(DM / 128, T_TOK / 128), 256, 0, stream>>>(
        o_ws, wot, b_O, out);
}

// Round 5
// 322.076 us; speedup vs baseline: 1.2970x; 1.1506x over previous
//
#include <hip/hip_runtime.h>
#include <hip/hip_bf16.h>

// ---- problem constants ----
#define B_SZ 4
#define S_SZ 2048
#define DM   1024
#define NH   8
#define DK   128
#define DC   32
#define DHR  32
#define DQK  160            // DK + DHR
#define T_TOK (B_SZ * S_SZ) // 8192
#define SCALE 0.07905694150420949f // 1/sqrt(160)
#define C2LOG 0.11405506439f       // SCALE * log2(e): softmax in exp2 domain
#define NT    (S_SZ / 64)   // 32 key tiles
#define NCOL  3328          // concat cols: UQ 1024 | QR 256 | UK 1024 | UV 1024

typedef unsigned int uint;
typedef unsigned short ushort;
typedef __attribute__((ext_vector_type(8))) short short8;
typedef __attribute__((ext_vector_type(4))) float floatx4;
typedef __attribute__((ext_vector_type(16))) float floatx16;
typedef __attribute__((ext_vector_type(4))) uint uintx4;

__device__ __forceinline__ ushort f2bf(float f) {
    uint u = __float_as_uint(f);
    uint r = u + 0x7fffu + ((u >> 16) & 1u);
    return (ushort)(r >> 16);
}
__device__ __forceinline__ uint packbf(float x, float y) {
    return (uint)f2bf(x) | ((uint)f2bf(y) << 16);
}

// async global->LDS, 16B per lane; lds dest = wave-uniform base + lane*16
__device__ __forceinline__ void glds16(const ushort* g, ushort* l) {
    __builtin_amdgcn_global_load_lds(
        (const __attribute__((address_space(1))) uint*)g,
        (__attribute__((address_space(3))) uint*)l, 16, 0, 0);
}

// ============================================================
// Kernel 1: cq/ckv/kr (bf16) = h_t @ {W_DQ, W_DKV, W_KR} + bias
// (round-5: emits bf16 directly; fp32 copies dropped)
// ============================================================
__global__ __launch_bounds__(256) void latent_kernel(
    const float* __restrict__ h_t,
    const float* __restrict__ W_DQ, const float* __restrict__ b_DQ,
    const float* __restrict__ W_DKV, const float* __restrict__ b_DKV,
    const float* __restrict__ W_KR, const float* __restrict__ b_KR,
    ushort* __restrict__ cqbf, ushort* __restrict__ ckvbf, ushort* __restrict__ krbf)
{
    __shared__ __align__(16) float hs[32 * 33];
    __shared__ __align__(16) float wq[32 * 32];
    __shared__ __align__(16) float wkv[32 * 32];
    __shared__ __align__(16) float wkr[32 * 32];

    const int tid = threadIdx.x;
    const int t0 = blockIdx.x * 32;
    const int t = tid & 31;
    const int g = tid >> 5;

    float acc_q[4] = {0.f, 0.f, 0.f, 0.f};
    float acc_kv[4] = {0.f, 0.f, 0.f, 0.f};
    float acc_kr[4] = {0.f, 0.f, 0.f, 0.f};

    const int lr = tid >> 3;
    const int lc = (tid & 7) * 4;

    for (int k0 = 0; k0 < DM; k0 += 32) {
        __syncthreads();
        {
            float4 v = *(const float4*)&h_t[(size_t)(t0 + lr) * DM + k0 + lc];
            hs[lr * 33 + lc + 0] = v.x;
            hs[lr * 33 + lc + 1] = v.y;
            hs[lr * 33 + lc + 2] = v.z;
            hs[lr * 33 + lc + 3] = v.w;
        }
        {
            float4 a = *(const float4*)&W_DQ[(size_t)(k0 + lr) * 32 + lc];
            wq[lr * 32 + lc + 0] = a.x; wq[lr * 32 + lc + 1] = a.y;
            wq[lr * 32 + lc + 2] = a.z; wq[lr * 32 + lc + 3] = a.w;
            float4 b = *(const float4*)&W_DKV[(size_t)(k0 + lr) * 32 + lc];
            wkv[lr * 32 + lc + 0] = b.x; wkv[lr * 32 + lc + 1] = b.y;
            wkv[lr * 32 + lc + 2] = b.z; wkv[lr * 32 + lc + 3] = b.w;
            float4 c = *(const float4*)&W_KR[(size_t)(k0 + lr) * 32 + lc];
            wkr[lr * 32 + lc + 0] = c.x; wkr[lr * 32 + lc + 1] = c.y;
            wkr[lr * 32 + lc + 2] = c.z; wkr[lr * 32 + lc + 3] = c.w;
        }
        __syncthreads();
        #pragma unroll 8
        for (int kk = 0; kk < 32; ++kk) {
            float a = hs[t * 33 + kk];
            #pragma unroll
            for (int cc = 0; cc < 4; ++cc) {
                int c = g * 4 + cc;
                acc_q[cc] += a * wq[kk * 32 + c];
                acc_kv[cc] += a * wkv[kk * 32 + c];
                acc_kr[cc] += a * wkr[kk * 32 + c];
            }
        }
    }
    #pragma unroll
    for (int cc = 0; cc < 4; ++cc) {
        int c = g * 4 + cc;
        int idx = (t0 + t) * 32 + c;
        cqbf[idx]  = f2bf(acc_q[cc] + b_DQ[c]);
        ckvbf[idx] = f2bf(acc_kv[cc] + b_DKV[c]);
        krbf[idx]  = f2bf(acc_kr[cc] + b_KR[c]);
    }
}

// ============================================================
// Kernel 2a (round-5): concat-transpose up-proj weights to bf16
// wcat [3328 cols][32 k] + bcat [3328] f32 bias.
// Col order: UQ(1024) | QR(256) | UK(1024) | UV(1024).
// ============================================================
__global__ __launch_bounds__(256) void wprep_kernel(
    const float* __restrict__ W_UQ, const float* __restrict__ b_UQ,
    const float* __restrict__ W_QR, const float* __restrict__ b_QR,
    const float* __restrict__ W_UK, const float* __restrict__ b_UK,
    const float* __restrict__ W_UV, const float* __restrict__ b_UV,
    ushort* __restrict__ wcat, float* __restrict__ bcat)
{
    __shared__ float t[32][33];
    const int tx = threadIdx.x & 31, ty = threadIdx.x >> 5;
    const int c0 = blockIdx.x * 32;

    const float* W; const float* bias; int stride, sc0;
    if (c0 < 1024)      { W = W_UQ; bias = b_UQ; stride = 1024; sc0 = c0; }
    else if (c0 < 1280) { W = W_QR; bias = b_QR; stride = 256;  sc0 = c0 - 1024; }
    else if (c0 < 2304) { W = W_UK; bias = b_UK; stride = 1024; sc0 = c0 - 1280; }
    else                { W = W_UV; bias = b_UV; stride = 1024; sc0 = c0 - 2304; }

    #pragma unroll
    for (int j = 0; j < 4; ++j) {
        int k = ty + j * 8;
        t[k][tx] = W[(size_t)k * stride + sc0 + tx];
    }
    __syncthreads();
    #pragma unroll
    for (int j = 0; j < 4; ++j) {
        int cc = ty + j * 8;
        wcat[(size_t)(c0 + cc) * 32 + tx] = f2bf(t[tx][cc]);
    }
    if (threadIdx.x < 32) bcat[c0 + threadIdx.x] = bias[sc0 + threadIdx.x];
}

// ============================================================
// Kernel 2b (round-5): build q/k/v via MFMA. K=32 == one
// mfma_f32_16x16x32_bf16 per 16-token x 16-col tile.
// D[m=col][n=token]: A = wcat row (natural), B = c row (natural).
// C/D layout (verified m89/m91): col(n)=lane&15, row(m)=quad*4+r ->
// each lane packs 4 consecutive d into one 8B store.
// Grid (T_TOK/64, 4 head-pairs), 256 thr; 52 MFMAs/wave. No LDS.
// ============================================================
__global__ __launch_bounds__(256) void build_qkv_mfma_kernel(
    const ushort* __restrict__ cqbf, const ushort* __restrict__ ckvbf,
    const ushort* __restrict__ krbf,
    const ushort* __restrict__ wcat, const float* __restrict__ bcat,
    ushort* __restrict__ q_ws, ushort* __restrict__ k_ws, ushort* __restrict__ v_ws)
{
    const int tid  = threadIdx.x;
    const int wave = tid >> 6;
    const int lane = tid & 63;
    const int quad = lane >> 4;
    const int l16  = lane & 15;

    const int tok = blockIdx.x * 64 + wave * 16 + l16;
    const int hp  = blockIdx.y;           // head pair 0..3
    const int bb  = tok >> 11, s = tok & 2047;

    // B fragments (k = quad*8 + j), natural row-major c layout
    const short8 bq  = *(const short8*)&cqbf[tok * 32 + quad * 8];
    const short8 bkv = *(const short8*)&ckvbf[tok * 32 + quad * 8];
    const uint4  kr  = *(const uint4*)&((const uint*)krbf)[tok * 16 + quad * 4];

    const int q4 = quad * 4;

    auto emit = [&](int wrow, ushort* outp, int dbase, short8 bfrag) {
        short8 af = *(const short8*)&wcat[(size_t)(wrow + l16) * 32 + quad * 8];
        floatx4 d = __builtin_amdgcn_mfma_f32_16x16x32_bf16(
            af, bfrag, (floatx4){0.f, 0.f, 0.f, 0.f}, 0, 0, 0);
        float4 b4 = *(const float4*)&bcat[wrow + q4];
        uint w0, w1;
        asm("v_cvt_pk_bf16_f32 %0, %1, %2" : "=v"(w0)
            : "v"(d[0] + b4.x), "v"(d[1] + b4.y));
        asm("v_cvt_pk_bf16_f32 %0, %1, %2" : "=v"(w1)
            : "v"(d[2] + b4.z), "v"(d[3] + b4.w));
        *(uint2*)&outp[dbase + q4] = make_uint2(w0, w1);
    };

    #pragma unroll
    for (int hh = 0; hh < 2; ++hh) {
        const int h = hp * 2 + hh;
        ushort* qp = q_ws + ((size_t)(bb * NH + h) * S_SZ + s) * DQK;
        ushort* kp = k_ws + ((size_t)(bb * NH + h) * S_SZ + s) * DQK;
        ushort* vp = v_ws + ((size_t)(bb * NH + h) * S_SZ + s) * DK;

        #pragma unroll
        for (int seg = 0; seg < 8; ++seg) emit(h * 128 + seg * 16, qp, seg * 16, bq);
        #pragma unroll
        for (int seg = 0; seg < 2; ++seg) emit(1024 + h * 32 + seg * 16, qp, 128 + seg * 16, bq);
        #pragma unroll
        for (int seg = 0; seg < 8; ++seg) emit(1280 + h * 128 + seg * 16, kp, seg * 16, bkv);
        #pragma unroll
        for (int seg = 0; seg < 8; ++seg) emit(2304 + h * 128 + seg * 16, vp, seg * 16, bkv);

        // k_r broadcast part: d 128..159 straight copy
        *(uint4*)&kp[128 + quad * 8] = kr;
    }
}

// ============================================================
// Kernel 3: 32x32x16-MFMA flash attention (unchanged from round 4)
// ============================================================
__global__ __launch_bounds__(256, 2) void attn_mfma_kernel(
    const ushort* __restrict__ q_ws, const ushort* __restrict__ k_ws,
    const ushort* __restrict__ v_ws, ushort* __restrict__ o_ws)
{
    __shared__ __align__(16) ushort SH[38912]; // 77824 B
    // us offsets: Ks buf0 @0, buf1 @10240; Vt buf0 @20480, buf1 @29696
    const int tid  = threadIdx.x;
    const int wave = tid >> 6;   // 0..3
    const int lane = tid & 63;
    const int l32  = lane & 31;
    const int hi   = lane >> 5;
    const int hi8  = hi * 8;

    // XCD-aware de-swizzle (8 XCDs, 512 blocks -> bijective)
    const int wg = blockIdx.x;
    const int virt = (wg & 7) * 64 + (wg >> 3);
    const int bh = virt >> 4;
    const int b = bh >> 3, h = bh & 7;
    const int s0 = (virt & 15) * 128;
    const int qrow_base = s0 + wave * 32;

    const ushort* kbase = k_ws + (size_t)bh * S_SZ * DQK;
    const ushort* vbase = v_ws + (size_t)bh * S_SZ * DK;

    // ---- K staging source offsets (inverse of read-side XOR swizzle).
    int ksrc[5];
    #pragma unroll
    for (int j = 0; j < 5; ++j) {
        int d = (tid + j * 256) * 16;
        int r0 = d / 320;
        int la = d;
        #pragma unroll
        for (int dr = -1; dr <= 1; ++dr) {
            int r = r0 + dr;
            int cand = d ^ ((r & 7) << 4);
            if (cand / 320 == r) la = cand;
        }
        ksrc[j] = la;
    }
    // per-wave-uniform LDS dest base (HW adds lane*16B)
    const int kdst_us = (wave * 64) * 8; // + j*256*8, + buf*10240

    // Q fragments: B[k = st*16 + hi*8 + j][qcol = l32], 10 k-steps of 16
    short8 qf[10];
    {
        const ushort* qp = q_ws + ((size_t)bh * S_SZ + qrow_base + l32) * DQK + hi8;
        #pragma unroll
        for (int st = 0; st < 10; ++st)
            qf[st] = *(const short8*)&qp[st * 16];
    }

    floatx16 oa[4];  // O^T: col=qrow(l32), row d = vt*32 + (r&3)+8*(r>>2)+4*hi
    #pragma unroll
    for (int vt = 0; vt < 4; ++vt)
        oa[vt] = (floatx16){0.f,0.f,0.f,0.f,0.f,0.f,0.f,0.f,
                            0.f,0.f,0.f,0.f,0.f,0.f,0.f,0.f};

    float m2 = -3.0e38f;   // running max in exp2-scaled domain
    float l_run = 0.f;

    // ---- prologue: stage tile 0 into buf 0
    {
        #pragma unroll
        for (int j = 0; j < 5; ++j)
            glds16((const ushort*)((const char*)kbase + ksrc[j]),
                   SH + kdst_us + j * 2048);
        uint vpa[8], vpb[8];
        const uint* vg = (const uint*)vbase;
        #pragma unroll
        for (int c = 0; c < 8; ++c) {
            int kp = wave * 8 + c;
            vpa[c] = vg[(2 * kp) * 64 + lane];
            vpb[c] = vg[(2 * kp + 1) * 64 + lane];
        }
        uint* vt32 = (uint*)(SH + 20480);
        uint lo[8], hh[8];
        #pragma unroll
        for (int c = 0; c < 8; ++c) {
            lo[c] = (vpa[c] & 0xffffu) | (vpb[c] << 16);
            hh[c] = (vpa[c] >> 16) | (vpb[c] & 0xffff0000u);
        }
        *(uint4*)&vt32[(2 * lane) * 36 + wave * 8]     = make_uint4(lo[0], lo[1], lo[4], lo[5]);
        *(uint4*)&vt32[(2 * lane) * 36 + wave * 8 + 4] = make_uint4(lo[2], lo[3], lo[6], lo[7]);
        *(uint4*)&vt32[(2 * lane + 1) * 36 + wave * 8]     = make_uint4(hh[0], hh[1], hh[4], hh[5]);
        *(uint4*)&vt32[(2 * lane + 1) * 36 + wave * 8 + 4] = make_uint4(hh[2], hh[3], hh[6], hh[7]);
    }

    const int kmask = (l32 & 7) << 4;

    for (int kt = 0; kt < NT; ++kt) {
        const int cur = kt & 1, nxt = cur ^ 1;
        __syncthreads(); // drains prev gl_lds + ds_writes; buf[cur] ready

        // ---- issue next tile's K DMA + V loads (latency hides under compute)
        uint vpa[8], vpb[8];
        if (kt + 1 < NT) {
            const char* kg = (const char*)(kbase + (size_t)(kt + 1) * 64 * DQK);
            #pragma unroll
            for (int j = 0; j < 5; ++j)
                glds16((const ushort*)(kg + ksrc[j]),
                       SH + nxt * 10240 + kdst_us + j * 2048);
            const uint* vg = (const uint*)(vbase + (size_t)(kt + 1) * 64 * DK);
            #pragma unroll
            for (int c = 0; c < 8; ++c) {
                int kp = wave * 8 + c;
                vpa[c] = vg[(2 * kp) * 64 + lane];
                vpb[c] = vg[(2 * kp + 1) * 64 + lane];
            }
        }

        // ---- Sc^T = K.Q^T : D[m=key][n=qrow], 2 key-blocks of 32
        const char* kbufc = (const char*)(SH + cur * 10240);
        floatx16 sc[2];
        __builtin_amdgcn_s_setprio(1);
        #pragma unroll
        for (int kb = 0; kb < 2; ++kb) {
            floatx16 acc = (floatx16){0.f,0.f,0.f,0.f,0.f,0.f,0.f,0.f,
                                      0.f,0.f,0.f,0.f,0.f,0.f,0.f,0.f};
            const int row_la = (kb * 32 + l32) * 320 + hi * 16;
            #pragma unroll
            for (int st = 0; st < 10; ++st) {
                short8 kf = *(const short8*)(kbufc + ((row_la + st * 32) ^ kmask));
                acc = __builtin_amdgcn_mfma_f32_32x32x16_bf16(kf, qf[st], acc, 0, 0, 0);
            }
            sc[kb] = acc;
        }
        __builtin_amdgcn_s_setprio(0);

        // ---- online softmax, exp2 domain, defer-rescale (T13, THR=8)
        {
            float tmax = -3.0e38f;
            #pragma unroll
            for (int kb = 0; kb < 2; ++kb)
                #pragma unroll
                for (int r = 0; r < 16; ++r)
                    tmax = fmaxf(tmax, sc[kb][r]);
            tmax *= C2LOG;
            tmax = fmaxf(tmax, __shfl_xor(tmax, 32));

            if (__any(tmax > m2 + 8.0f)) {
                float mnew = fmaxf(m2, tmax);
                float al = __builtin_amdgcn_exp2f(m2 - mnew);
                m2 = mnew;
                l_run *= al;
                #pragma unroll
                for (int vt = 0; vt < 4; ++vt)
                    #pragma unroll
                    for (int r = 0; r < 16; ++r)
                        oa[vt][r] *= al;
            }

            float rsum = 0.f;
            #pragma unroll
            for (int kb = 0; kb < 2; ++kb)
                #pragma unroll
                for (int r = 0; r < 16; ++r) {
                    float p = __builtin_amdgcn_exp2f(__builtin_fmaf(sc[kb][r], C2LOG, -m2));
                    sc[kb][r] = p;
                    rsum += p;
                }
            rsum += __shfl_xor(rsum, 32);
            l_run += rsum;
        }

        // ---- O^T += V^T . P^T ; pf = in-lane cvt_pk of consecutive sc pairs
        const ushort* vtc = SH + 20480 + cur * 9216;
        __builtin_amdgcn_s_setprio(1);
        #pragma unroll
        for (int kb = 0; kb < 2; ++kb) {
            #pragma unroll
            for (int s = 0; s < 2; ++s) {
                uint w0, w1, w2, w3;
                asm("v_cvt_pk_bf16_f32 %0, %1, %2" : "=v"(w0)
                    : "v"(sc[kb][8 * s + 0]), "v"(sc[kb][8 * s + 1]));
                asm("v_cvt_pk_bf16_f32 %0, %1, %2" : "=v"(w1)
                    : "v"(sc[kb][8 * s + 2]), "v"(sc[kb][8 * s + 3]));
                asm("v_cvt_pk_bf16_f32 %0, %1, %2" : "=v"(w2)
                    : "v"(sc[kb][8 * s + 4]), "v"(sc[kb][8 * s + 5]));
                asm("v_cvt_pk_bf16_f32 %0, %1, %2" : "=v"(w3)
                    : "v"(sc[kb][8 * s + 6]), "v"(sc[kb][8 * s + 7]));
                short8 pv = __builtin_bit_cast(short8, (uintx4){w0, w1, w2, w3});
                #pragma unroll
                for (int vt = 0; vt < 4; ++vt) {
                    short8 vf = *(const short8*)&vtc[(size_t)(vt * 32 + l32) * 72
                                                     + kb * 32 + s * 16 + hi8];
                    oa[vt] = __builtin_amdgcn_mfma_f32_32x32x16_bf16(vf, pv, oa[vt], 0, 0, 0);
                }
            }
        }
        __builtin_amdgcn_s_setprio(0);

        // ---- late V stage into buf[nxt] (loads issued at tile top are done)
        if (kt + 1 < NT) {
            uint* vt32 = (uint*)(SH + 20480 + nxt * 9216);
            uint lo[8], hh[8];
            #pragma unroll
            for (int c = 0; c < 8; ++c) {
                lo[c] = (vpa[c] & 0xffffu) | (vpb[c] << 16);
                hh[c] = (vpa[c] >> 16) | (vpb[c] & 0xffff0000u);
            }
            *(uint4*)&vt32[(2 * lane) * 36 + wave * 8]     = make_uint4(lo[0], lo[1], lo[4], lo[5]);
            *(uint4*)&vt32[(2 * lane) * 36 + wave * 8 + 4] = make_uint4(lo[2], lo[3], lo[6], lo[7]);
            *(uint4*)&vt32[(2 * lane + 1) * 36 + wave * 8]     = make_uint4(hh[0], hh[1], hh[4], hh[5]);
            *(uint4*)&vt32[(2 * lane + 1) * 36 + wave * 8 + 4] = make_uint4(hh[2], hh[3], hh[6], hh[7]);
        }
    }

    // ---- epilogue: transpose O^T -> O through reused LDS, coalesced store
    __syncthreads(); // everyone done with K/V buffers
    ushort* ot = SH + wave * (32 * 136); // per-wave 32 rows x 136 us
    uint* ot32 = (uint*)ot;
    {
        float inv = 1.0f / l_run;
        #pragma unroll
        for (int vt = 0; vt < 4; ++vt)
            #pragma unroll
            for (int g = 0; g < 4; ++g) {
                int base = l32 * 68 + vt * 16 + g * 4 + hi * 2;
                ot32[base]     = packbf(oa[vt][g * 4 + 0] * inv, oa[vt][g * 4 + 1] * inv);
                ot32[base + 1] = packbf(oa[vt][g * 4 + 2] * inv, oa[vt][g * 4 + 3] * inv);
            }
    }
    // same-wave LDS ordering: no barrier needed
    #pragma unroll
    for (int pass = 0; pass < 8; ++pass) {
        int row_in = pass * 4 + (lane >> 4);
        int col8 = (lane & 15) * 8;
        uint4 v = *(const uint4*)&ot[row_in * 136 + col8];
        int srow = qrow_base + row_in;
        *(uint4*)(o_ws + (((size_t)b * S_SZ + srow) * NH + h) * DK + col8) = v;
    }
}

// ============================================================
// Kernel 4a: W_O [1024 k][1024 n] fp32 -> W_O^T bf16 [n][k] (unchanged)
// ============================================================
__global__ __launch_bounds__(256) void transpose_wo_kernel(
    const float* __restrict__ W_O, ushort* __restrict__ wot)
{
    __shared__ float t[32][33];
    const int tx = threadIdx.x & 31, ty = threadIdx.x >> 5;
    const int n0 = blockIdx.x * 32, k0 = blockIdx.y * 32;
    #pragma unroll
    for (int j = 0; j < 32; j += 8)
        t[ty + j][tx] = W_O[(size_t)(k0 + ty + j) * DM + n0 + tx];
    __syncthreads();
    #pragma unroll
    for (int j = 0; j < 32; j += 8)
        wot[(size_t)(n0 + ty + j) * DM + k0 + tx] = f2bf(t[tx][ty + j]);
}

// ============================================================
// Kernel 4b: out = o_ws @ W_O + b_O via MFMA (unchanged)
// ============================================================
__global__ __launch_bounds__(256) void out_gemm_mfma_kernel(
    const ushort* __restrict__ A,    // o_ws [8192][1024] bf16
    const ushort* __restrict__ BT,   // wot  [1024 n][1024 k] bf16
    const float* __restrict__ b_O, float* __restrict__ out)
{
    __shared__ __align__(16) ushort As[128 * 32];
    __shared__ __align__(16) ushort Bs[128 * 32];

    const int tid = threadIdx.x;
    const int wave = tid >> 6;
    const int lane = tid & 63;
    const int quad = lane >> 4;
    const int l16 = lane & 15;
    const int wr = wave >> 1, wc = wave & 1;

    const int n0 = blockIdx.x * 128;
    const int m0 = blockIdx.y * 128;

    const int lrow = lane >> 2;
    const int lseg = (lane & 3) * 8;

    floatx4 acc[4][4];
    #pragma unroll
    for (int mt = 0; mt < 4; ++mt)
        #pragma unroll
        for (int nt = 0; nt < 4; ++nt)
            acc[mt][nt] = (floatx4){0.f, 0.f, 0.f, 0.f};

    for (int k0 = 0; k0 < DM; k0 += 32) {
        __syncthreads();
        {
            const ushort* g0 = A + (size_t)(m0 + wave * 32 + lrow) * DM + k0 + lseg;
            glds16(g0, &As[(wave * 32) * 32]);
            const ushort* g1 = A + (size_t)(m0 + wave * 32 + 16 + lrow) * DM + k0 + lseg;
            glds16(g1, &As[(wave * 32 + 16) * 32]);
        }
        {
            const ushort* g0 = BT + (size_t)(n0 + wave * 32 + lrow) * DM + k0 + lseg;
            glds16(g0, &Bs[(wave * 32) * 32]);
            const ushort* g1 = BT + (size_t)(n0 + wave * 32 + 16 + lrow) * DM + k0 + lseg;
            glds16(g1, &Bs[(wave * 32 + 16) * 32]);
        }
        __syncthreads();

        short8 af[4], bf[4];
        #pragma unroll
        for (int mt = 0; mt < 4; ++mt)
            af[mt] = *(const short8*)&As[(wr * 64 + mt * 16 + l16) * 32 + quad * 8];
        #pragma unroll
        for (int nt = 0; nt < 4; ++nt)
            bf[nt] = *(const short8*)&Bs[(wc * 64 + nt * 16 + l16) * 32 + quad * 8];
        #pragma unroll
        for (int mt = 0; mt < 4; ++mt)
            #pragma unroll
            for (int nt = 0; nt < 4; ++nt)
                acc[mt][nt] = __builtin_amdgcn_mfma_f32_16x16x32_bf16(af[mt], bf[nt], acc[mt][nt], 0, 0, 0);
    }

    float bo[4];
    #pragma unroll
    for (int nt = 0; nt < 4; ++nt) bo[nt] = b_O[n0 + wc * 64 + nt * 16 + l16];

    #pragma unroll
    for (int mt = 0; mt < 4; ++mt) {
        #pragma unroll
        for (int r = 0; r < 4; ++r) {
            int row = m0 + wr * 64 + mt * 16 + quad * 4 + r;
            float* orow = out + (size_t)row * DM + n0 + wc * 64;
            #pragma unroll
            for (int nt = 0; nt < 4; ++nt)
                orow[nt * 16 + l16] = acc[mt][nt][r] + bo[nt];
        }
    }
}

// ============================================================
extern "C" void kernel_launch(void* const* d_in, const int* in_sizes, int n_in,
                              void* d_out, int out_size, void* d_ws, size_t ws_size,
                              hipStream_t stream) {
    (void)in_sizes; (void)n_in; (void)out_size; (void)ws_size;

    const float* h_t   = (const float*)d_in[0];
    const float* W_DQ  = (const float*)d_in[1];
    const float* b_DQ  = (const float*)d_in[2];
    const float* W_UQ  = (const float*)d_in[3];
    const float* b_UQ  = (const float*)d_in[4];
    const float* W_DKV = (const float*)d_in[5];
    const float* b_DKV = (const float*)d_in[6];
    const float* W_UK  = (const float*)d_in[7];
    const float* b_UK  = (const float*)d_in[8];
    const float* W_UV  = (const float*)d_in[9];
    const float* b_UV  = (const float*)d_in[10];
    const float* W_QR  = (const float*)d_in[11];
    const float* b_QR  = (const float*)d_in[12];
    const float* W_KR  = (const float*)d_in[13];
    const float* b_KR  = (const float*)d_in[14];
    const float* W_O   = (const float*)d_in[15];
    const float* b_O   = (const float*)d_in[16];

    ushort* cqbf  = (ushort*)d_ws;                      // [8192][32]
    ushort* ckvbf = cqbf + (size_t)T_TOK * DC;
    ushort* krbf  = ckvbf + (size_t)T_TOK * DC;
    ushort* wcat  = krbf + (size_t)T_TOK * DC;          // [3328][32]
    float*  bcat  = (float*)(wcat + (size_t)NCOL * DC); // [3328]
    ushort* q_ws  = (ushort*)(bcat + NCOL);
    ushort* k_ws  = q_ws + (size_t)B_SZ * NH * S_SZ * DQK;
    ushort* v_ws  = k_ws + (size_t)B_SZ * NH * S_SZ * DQK;
    ushort* o_ws  = v_ws + (size_t)B_SZ * NH * S_SZ * DK;
    ushort* wot   = o_ws + (size_t)T_TOK * DM;

    float* out = (float*)d_out;

    latent_kernel<<<T_TOK / 32, 256, 0, stream>>>(
        h_t, W_DQ, b_DQ, W_DKV, b_DKV, W_KR, b_KR, cqbf, ckvbf, krbf);

    wprep_kernel<<<NCOL / 32, 256, 0, stream>>>(
        W_UQ, b_UQ, W_QR, b_QR, W_UK, b_UK, W_UV, b_UV, wcat, bcat);

    transpose_wo_kernel<<<dim3(32, 32), 256, 0, stream>>>(W_O, wot);

    build_qkv_mfma_kernel<<<dim3(T_TOK / 64, 4), 256, 0, stream>>>(
        cqbf, ckvbf, krbf, wcat, bcat, q_ws, k_ws, v_ws);

    attn_mfma_kernel<<<512, 256, 0, stream>>>(
        q_ws, k_ws, v_ws, o_ws);

    out_gemm_mfma_kernel<<<dim3(DM / 128, T_TOK / 128), 256, 0, stream>>>(
        o_ws, wot, b_O, out);
}

// Round 6
// 270.923 us; speedup vs baseline: 1.5419x; 1.1888x over previous
//
#include <hip/hip_runtime.h>
#include <hip/hip_bf16.h>

// ---- problem constants ----
#define B_SZ 4
#define S_SZ 2048
#define DM   1024
#define NH   8
#define DK   128
#define DC   32
#define DHR  32
#define DQK  160            // DK + DHR
#define T_TOK (B_SZ * S_SZ) // 8192
#define SCALE 0.07905694150420949f // 1/sqrt(160)
#define C2LOG 0.11405506439f       // SCALE * log2(e): softmax in exp2 domain
#define NT    (S_SZ / 64)   // 32 key tiles
#define NCOL  3328          // concat cols: UQ 1024 | QR 256 | UK 1024 | UV 1024

typedef unsigned int uint;
typedef unsigned short ushort;
typedef __attribute__((ext_vector_type(8))) short short8;
typedef __attribute__((ext_vector_type(4))) float floatx4;
typedef __attribute__((ext_vector_type(16))) float floatx16;
typedef __attribute__((ext_vector_type(4))) uint uintx4;

__device__ __forceinline__ ushort f2bf(float f) {
    uint u = __float_as_uint(f);
    uint r = u + 0x7fffu + ((u >> 16) & 1u);
    return (ushort)(r >> 16);
}
__device__ __forceinline__ uint packbf(float x, float y) {
    return (uint)f2bf(x) | ((uint)f2bf(y) << 16);
}

// async global->LDS, 16B per lane; lds dest = wave-uniform base + lane*16
__device__ __forceinline__ void glds16(const ushort* g, ushort* l) {
    __builtin_amdgcn_global_load_lds(
        (const __attribute__((address_space(1))) uint*)g,
        (__attribute__((address_space(3))) uint*)l, 16, 0, 0);
}

// ============================================================
// Kernel P (round-6): merged prep — one launch, role by blockIdx.
//  [0,1024)   : W_O fp32 -> wot bf16 [n][k]   (transpose_wo)
//  [1024,1128): up-proj concat wcat [3328][32] + bcat
//  [1128,1224): down-proj concat-T wdcat [96][1024] + bdcat
//               col order: DQ(32) | DKV(32) | KR(32)
// ============================================================
__global__ __launch_bounds__(256) void prep_kernel(
    const float* __restrict__ W_O,
    const float* __restrict__ W_UQ, const float* __restrict__ b_UQ,
    const float* __restrict__ W_QR, const float* __restrict__ b_QR,
    const float* __restrict__ W_UK, const float* __restrict__ b_UK,
    const float* __restrict__ W_UV, const float* __restrict__ b_UV,
    const float* __restrict__ W_DQ, const float* __restrict__ b_DQ,
    const float* __restrict__ W_DKV, const float* __restrict__ b_DKV,
    const float* __restrict__ W_KR, const float* __restrict__ b_KR,
    ushort* __restrict__ wot,
    ushort* __restrict__ wcat, float* __restrict__ bcat,
    ushort* __restrict__ wdcat, float* __restrict__ bdcat)
{
    __shared__ float t[32][33];
    const int bid = blockIdx.x;
    const int tx = threadIdx.x & 31, ty = threadIdx.x >> 5;

    if (bid < 1024) {
        const int n0 = (bid & 31) * 32, k0 = (bid >> 5) * 32;
        #pragma unroll
        for (int j = 0; j < 32; j += 8)
            t[ty + j][tx] = W_O[(size_t)(k0 + ty + j) * DM + n0 + tx];
        __syncthreads();
        #pragma unroll
        for (int j = 0; j < 32; j += 8)
            wot[(size_t)(n0 + ty + j) * DM + k0 + tx] = f2bf(t[tx][ty + j]);
    } else if (bid < 1128) {
        const int c0 = (bid - 1024) * 32;
        const float* W; const float* bias; int stride, sc0;
        if (c0 < 1024)      { W = W_UQ; bias = b_UQ; stride = 1024; sc0 = c0; }
        else if (c0 < 1280) { W = W_QR; bias = b_QR; stride = 256;  sc0 = c0 - 1024; }
        else if (c0 < 2304) { W = W_UK; bias = b_UK; stride = 1024; sc0 = c0 - 1280; }
        else                { W = W_UV; bias = b_UV; stride = 1024; sc0 = c0 - 2304; }
        #pragma unroll
        for (int j = 0; j < 4; ++j) {
            int k = ty + j * 8;
            t[k][tx] = W[(size_t)k * stride + sc0 + tx];
        }
        __syncthreads();
        #pragma unroll
        for (int j = 0; j < 4; ++j) {
            int cc = ty + j * 8;
            wcat[(size_t)(c0 + cc) * 32 + tx] = f2bf(t[tx][cc]);
        }
        if (threadIdx.x < 32) bcat[c0 + threadIdx.x] = bias[sc0 + threadIdx.x];
    } else {
        const int idx = bid - 1128;
        const int wsel = idx >> 5;          // 0..2
        const int k0 = (idx & 31) * 32;
        const float* W    = (wsel == 0) ? W_DQ  : (wsel == 1) ? W_DKV : W_KR;
        const float* bias = (wsel == 0) ? b_DQ  : (wsel == 1) ? b_DKV : b_KR;
        #pragma unroll
        for (int j = 0; j < 32; j += 8)
            t[ty + j][tx] = W[(size_t)(k0 + ty + j) * 32 + tx];
        __syncthreads();
        #pragma unroll
        for (int j = 0; j < 32; j += 8)
            wdcat[(size_t)(wsel * 32 + ty + j) * DM + k0 + tx] = f2bf(t[tx][ty + j]);
        if (k0 == 0 && threadIdx.x < 32)
            bdcat[wsel * 32 + threadIdx.x] = bias[threadIdx.x];
    }
}

// ============================================================
// Kernel 1 (round-6): latent projections via MFMA.
// D[m=latent-col 96][n=token]: A = wdcat row (bf16, L2-resident),
// B = h_t row fp32 -> in-register cvt_pk -> bf16 frag. No LDS.
// Grid 256 blocks x 128 thr (2 waves); wave = 16 tokens x 96 cols,
// 32 k-steps x (6 A-loads + 2 float4 B-loads + 4 cvt + 6 MFMA).
// ============================================================
__global__ __launch_bounds__(128) void latent_mfma_kernel(
    const float* __restrict__ h_t,
    const ushort* __restrict__ wdcat, const float* __restrict__ bdcat,
    ushort* __restrict__ cqbf, ushort* __restrict__ ckvbf, ushort* __restrict__ krbf)
{
    const int tid  = threadIdx.x;
    const int wave = tid >> 6;          // 0..1
    const int lane = tid & 63;
    const int quad = lane >> 4;
    const int l16  = lane & 15;

    const int tok = blockIdx.x * 32 + wave * 16 + l16;

    floatx4 acc[6];
    #pragma unroll
    for (int ct = 0; ct < 6; ++ct) acc[ct] = (floatx4){0.f, 0.f, 0.f, 0.f};

    const float* hrow = h_t + (size_t)tok * DM + quad * 8;

    #pragma unroll 2
    for (int k0 = 0; k0 < DM; k0 += 32) {
        float4 f0 = *(const float4*)&hrow[k0];
        float4 f1 = *(const float4*)&hrow[k0 + 4];
        uint b0, b1, b2, b3;
        asm("v_cvt_pk_bf16_f32 %0, %1, %2" : "=v"(b0) : "v"(f0.x), "v"(f0.y));
        asm("v_cvt_pk_bf16_f32 %0, %1, %2" : "=v"(b1) : "v"(f0.z), "v"(f0.w));
        asm("v_cvt_pk_bf16_f32 %0, %1, %2" : "=v"(b2) : "v"(f1.x), "v"(f1.y));
        asm("v_cvt_pk_bf16_f32 %0, %1, %2" : "=v"(b3) : "v"(f1.z), "v"(f1.w));
        short8 bf = __builtin_bit_cast(short8, (uintx4){b0, b1, b2, b3});
        #pragma unroll
        for (int ct = 0; ct < 6; ++ct) {
            short8 af = *(const short8*)&wdcat[(size_t)(ct * 16 + l16) * DM + k0 + quad * 8];
            acc[ct] = __builtin_amdgcn_mfma_f32_16x16x32_bf16(af, bf, acc[ct], 0, 0, 0);
        }
    }

    const int q4 = quad * 4;
    #pragma unroll
    for (int ct = 0; ct < 6; ++ct) {
        float4 b4 = *(const float4*)&bdcat[ct * 16 + q4];
        uint w0, w1;
        asm("v_cvt_pk_bf16_f32 %0, %1, %2" : "=v"(w0)
            : "v"(acc[ct][0] + b4.x), "v"(acc[ct][1] + b4.y));
        asm("v_cvt_pk_bf16_f32 %0, %1, %2" : "=v"(w1)
            : "v"(acc[ct][2] + b4.z), "v"(acc[ct][3] + b4.w));
        int col = ct * 16 + q4;
        ushort* outp = (col < 32) ? cqbf : (col < 64) ? ckvbf : krbf;
        int cc = col & 31;
        *(uint2*)&outp[(size_t)tok * 32 + cc] = make_uint2(w0, w1);
    }
}

// ============================================================
// Kernel 2b: build q/k/v via MFMA (unchanged from round 5)
// ============================================================
__global__ __launch_bounds__(256) void build_qkv_mfma_kernel(
    const ushort* __restrict__ cqbf, const ushort* __restrict__ ckvbf,
    const ushort* __restrict__ krbf,
    const ushort* __restrict__ wcat, const float* __restrict__ bcat,
    ushort* __restrict__ q_ws, ushort* __restrict__ k_ws, ushort* __restrict__ v_ws)
{
    const int tid  = threadIdx.x;
    const int wave = tid >> 6;
    const int lane = tid & 63;
    const int quad = lane >> 4;
    const int l16  = lane & 15;

    const int tok = blockIdx.x * 64 + wave * 16 + l16;
    const int hp  = blockIdx.y;           // head pair 0..3
    const int bb  = tok >> 11, s = tok & 2047;

    // B fragments (k = quad*8 + j), natural row-major c layout
    const short8 bq  = *(const short8*)&cqbf[tok * 32 + quad * 8];
    const short8 bkv = *(const short8*)&ckvbf[tok * 32 + quad * 8];
    const uint4  kr  = *(const uint4*)&((const uint*)krbf)[tok * 16 + quad * 4];

    const int q4 = quad * 4;

    auto emit = [&](int wrow, ushort* outp, int dbase, short8 bfrag) {
        short8 af = *(const short8*)&wcat[(size_t)(wrow + l16) * 32 + quad * 8];
        floatx4 d = __builtin_amdgcn_mfma_f32_16x16x32_bf16(
            af, bfrag, (floatx4){0.f, 0.f, 0.f, 0.f}, 0, 0, 0);
        float4 b4 = *(const float4*)&bcat[wrow + q4];
        uint w0, w1;
        asm("v_cvt_pk_bf16_f32 %0, %1, %2" : "=v"(w0)
            : "v"(d[0] + b4.x), "v"(d[1] + b4.y));
        asm("v_cvt_pk_bf16_f32 %0, %1, %2" : "=v"(w1)
            : "v"(d[2] + b4.z), "v"(d[3] + b4.w));
        *(uint2*)&outp[dbase + q4] = make_uint2(w0, w1);
    };

    #pragma unroll
    for (int hh = 0; hh < 2; ++hh) {
        const int h = hp * 2 + hh;
        ushort* qp = q_ws + ((size_t)(bb * NH + h) * S_SZ + s) * DQK;
        ushort* kp = k_ws + ((size_t)(bb * NH + h) * S_SZ + s) * DQK;
        ushort* vp = v_ws + ((size_t)(bb * NH + h) * S_SZ + s) * DK;

        #pragma unroll
        for (int seg = 0; seg < 8; ++seg) emit(h * 128 + seg * 16, qp, seg * 16, bq);
        #pragma unroll
        for (int seg = 0; seg < 2; ++seg) emit(1024 + h * 32 + seg * 16, qp, 128 + seg * 16, bq);
        #pragma unroll
        for (int seg = 0; seg < 8; ++seg) emit(1280 + h * 128 + seg * 16, kp, seg * 16, bkv);
        #pragma unroll
        for (int seg = 0; seg < 8; ++seg) emit(2304 + h * 128 + seg * 16, vp, seg * 16, bkv);

        // k_r broadcast part: d 128..159 straight copy
        *(uint4*)&kp[128 + quad * 8] = kr;
    }
}

// ============================================================
// Kernel 3: 32x32x16-MFMA flash attention (unchanged from round 4)
// ============================================================
__global__ __launch_bounds__(256, 2) void attn_mfma_kernel(
    const ushort* __restrict__ q_ws, const ushort* __restrict__ k_ws,
    const ushort* __restrict__ v_ws, ushort* __restrict__ o_ws)
{
    __shared__ __align__(16) ushort SH[38912]; // 77824 B
    // us offsets: Ks buf0 @0, buf1 @10240; Vt buf0 @20480, buf1 @29696
    const int tid  = threadIdx.x;
    const int wave = tid >> 6;   // 0..3
    const int lane = tid & 63;
    const int l32  = lane & 31;
    const int hi   = lane >> 5;
    const int hi8  = hi * 8;

    // XCD-aware de-swizzle (8 XCDs, 512 blocks -> bijective)
    const int wg = blockIdx.x;
    const int virt = (wg & 7) * 64 + (wg >> 3);
    const int bh = virt >> 4;
    const int b = bh >> 3, h = bh & 7;
    const int s0 = (virt & 15) * 128;
    const int qrow_base = s0 + wave * 32;

    const ushort* kbase = k_ws + (size_t)bh * S_SZ * DQK;
    const ushort* vbase = v_ws + (size_t)bh * S_SZ * DK;

    // ---- K staging source offsets (inverse of read-side XOR swizzle).
    int ksrc[5];
    #pragma unroll
    for (int j = 0; j < 5; ++j) {
        int d = (tid + j * 256) * 16;
        int r0 = d / 320;
        int la = d;
        #pragma unroll
        for (int dr = -1; dr <= 1; ++dr) {
            int r = r0 + dr;
            int cand = d ^ ((r & 7) << 4);
            if (cand / 320 == r) la = cand;
        }
        ksrc[j] = la;
    }
    // per-wave-uniform LDS dest base (HW adds lane*16B)
    const int kdst_us = (wave * 64) * 8; // + j*256*8, + buf*10240

    // Q fragments: B[k = st*16 + hi*8 + j][qcol = l32], 10 k-steps of 16
    short8 qf[10];
    {
        const ushort* qp = q_ws + ((size_t)bh * S_SZ + qrow_base + l32) * DQK + hi8;
        #pragma unroll
        for (int st = 0; st < 10; ++st)
            qf[st] = *(const short8*)&qp[st * 16];
    }

    floatx16 oa[4];  // O^T: col=qrow(l32), row d = vt*32 + (r&3)+8*(r>>2)+4*hi
    #pragma unroll
    for (int vt = 0; vt < 4; ++vt)
        oa[vt] = (floatx16){0.f,0.f,0.f,0.f,0.f,0.f,0.f,0.f,
                            0.f,0.f,0.f,0.f,0.f,0.f,0.f,0.f};

    float m2 = -3.0e38f;   // running max in exp2-scaled domain
    float l_run = 0.f;

    // ---- prologue: stage tile 0 into buf 0
    {
        #pragma unroll
        for (int j = 0; j < 5; ++j)
            glds16((const ushort*)((const char*)kbase + ksrc[j]),
                   SH + kdst_us + j * 2048);
        uint vpa[8], vpb[8];
        const uint* vg = (const uint*)vbase;
        #pragma unroll
        for (int c = 0; c < 8; ++c) {
            int kp = wave * 8 + c;
            vpa[c] = vg[(2 * kp) * 64 + lane];
            vpb[c] = vg[(2 * kp + 1) * 64 + lane];
        }
        uint* vt32 = (uint*)(SH + 20480);
        uint lo[8], hh[8];
        #pragma unroll
        for (int c = 0; c < 8; ++c) {
            lo[c] = (vpa[c] & 0xffffu) | (vpb[c] << 16);
            hh[c] = (vpa[c] >> 16) | (vpb[c] & 0xffff0000u);
        }
        *(uint4*)&vt32[(2 * lane) * 36 + wave * 8]     = make_uint4(lo[0], lo[1], lo[4], lo[5]);
        *(uint4*)&vt32[(2 * lane) * 36 + wave * 8 + 4] = make_uint4(lo[2], lo[3], lo[6], lo[7]);
        *(uint4*)&vt32[(2 * lane + 1) * 36 + wave * 8]     = make_uint4(hh[0], hh[1], hh[4], hh[5]);
        *(uint4*)&vt32[(2 * lane + 1) * 36 + wave * 8 + 4] = make_uint4(hh[2], hh[3], hh[6], hh[7]);
    }

    const int kmask = (l32 & 7) << 4;

    for (int kt = 0; kt < NT; ++kt) {
        const int cur = kt & 1, nxt = cur ^ 1;
        __syncthreads(); // drains prev gl_lds + ds_writes; buf[cur] ready

        // ---- issue next tile's K DMA + V loads (latency hides under compute)
        uint vpa[8], vpb[8];
        if (kt + 1 < NT) {
            const char* kg = (const char*)(kbase + (size_t)(kt + 1) * 64 * DQK);
            #pragma unroll
            for (int j = 0; j < 5; ++j)
                glds16((const ushort*)(kg + ksrc[j]),
                       SH + nxt * 10240 + kdst_us + j * 2048);
            const uint* vg = (const uint*)(vbase + (size_t)(kt + 1) * 64 * DK);
            #pragma unroll
            for (int c = 0; c < 8; ++c) {
                int kp = wave * 8 + c;
                vpa[c] = vg[(2 * kp) * 64 + lane];
                vpb[c] = vg[(2 * kp + 1) * 64 + lane];
            }
        }

        // ---- Sc^T = K.Q^T : D[m=key][n=qrow], 2 key-blocks of 32
        const char* kbufc = (const char*)(SH + cur * 10240);
        floatx16 sc[2];
        __builtin_amdgcn_s_setprio(1);
        #pragma unroll
        for (int kb = 0; kb < 2; ++kb) {
            floatx16 acc = (floatx16){0.f,0.f,0.f,0.f,0.f,0.f,0.f,0.f,
                                      0.f,0.f,0.f,0.f,0.f,0.f,0.f,0.f};
            const int row_la = (kb * 32 + l32) * 320 + hi * 16;
            #pragma unroll
            for (int st = 0; st < 10; ++st) {
                short8 kf = *(const short8*)(kbufc + ((row_la + st * 32) ^ kmask));
                acc = __builtin_amdgcn_mfma_f32_32x32x16_bf16(kf, qf[st], acc, 0, 0, 0);
            }
            sc[kb] = acc;
        }
        __builtin_amdgcn_s_setprio(0);

        // ---- online softmax, exp2 domain, defer-rescale (T13, THR=8)
        {
            float tmax = -3.0e38f;
            #pragma unroll
            for (int kb = 0; kb < 2; ++kb)
                #pragma unroll
                for (int r = 0; r < 16; ++r)
                    tmax = fmaxf(tmax, sc[kb][r]);
            tmax *= C2LOG;
            tmax = fmaxf(tmax, __shfl_xor(tmax, 32));

            if (__any(tmax > m2 + 8.0f)) {
                float mnew = fmaxf(m2, tmax);
                float al = __builtin_amdgcn_exp2f(m2 - mnew);
                m2 = mnew;
                l_run *= al;
                #pragma unroll
                for (int vt = 0; vt < 4; ++vt)
                    #pragma unroll
                    for (int r = 0; r < 16; ++r)
                        oa[vt][r] *= al;
            }

            float rsum = 0.f;
            #pragma unroll
            for (int kb = 0; kb < 2; ++kb)
                #pragma unroll
                for (int r = 0; r < 16; ++r) {
                    float p = __builtin_amdgcn_exp2f(__builtin_fmaf(sc[kb][r], C2LOG, -m2));
                    sc[kb][r] = p;
                    rsum += p;
                }
            rsum += __shfl_xor(rsum, 32);
            l_run += rsum;
        }

        // ---- O^T += V^T . P^T ; pf = in-lane cvt_pk of consecutive sc pairs
        const ushort* vtc = SH + 20480 + cur * 9216;
        __builtin_amdgcn_s_setprio(1);
        #pragma unroll
        for (int kb = 0; kb < 2; ++kb) {
            #pragma unroll
            for (int s = 0; s < 2; ++s) {
                uint w0, w1, w2, w3;
                asm("v_cvt_pk_bf16_f32 %0, %1, %2" : "=v"(w0)
                    : "v"(sc[kb][8 * s + 0]), "v"(sc[kb][8 * s + 1]));
                asm("v_cvt_pk_bf16_f32 %0, %1, %2" : "=v"(w1)
                    : "v"(sc[kb][8 * s + 2]), "v"(sc[kb][8 * s + 3]));
                asm("v_cvt_pk_bf16_f32 %0, %1, %2" : "=v"(w2)
                    : "v"(sc[kb][8 * s + 4]), "v"(sc[kb][8 * s + 5]));
                asm("v_cvt_pk_bf16_f32 %0, %1, %2" : "=v"(w3)
                    : "v"(sc[kb][8 * s + 6]), "v"(sc[kb][8 * s + 7]));
                short8 pv = __builtin_bit_cast(short8, (uintx4){w0, w1, w2, w3});
                #pragma unroll
                for (int vt = 0; vt < 4; ++vt) {
                    short8 vf = *(const short8*)&vtc[(size_t)(vt * 32 + l32) * 72
                                                     + kb * 32 + s * 16 + hi8];
                    oa[vt] = __builtin_amdgcn_mfma_f32_32x32x16_bf16(vf, pv, oa[vt], 0, 0, 0);
                }
            }
        }
        __builtin_amdgcn_s_setprio(0);

        // ---- late V stage into buf[nxt] (loads issued at tile top are done)
        if (kt + 1 < NT) {
            uint* vt32 = (uint*)(SH + 20480 + nxt * 9216);
            uint lo[8], hh[8];
            #pragma unroll
            for (int c = 0; c < 8; ++c) {
                lo[c] = (vpa[c] & 0xffffu) | (vpb[c] << 16);
                hh[c] = (vpa[c] >> 16) | (vpb[c] & 0xffff0000u);
            }
            *(uint4*)&vt32[(2 * lane) * 36 + wave * 8]     = make_uint4(lo[0], lo[1], lo[4], lo[5]);
            *(uint4*)&vt32[(2 * lane) * 36 + wave * 8 + 4] = make_uint4(lo[2], lo[3], lo[6], lo[7]);
            *(uint4*)&vt32[(2 * lane + 1) * 36 + wave * 8]     = make_uint4(hh[0], hh[1], hh[4], hh[5]);
            *(uint4*)&vt32[(2 * lane + 1) * 36 + wave * 8 + 4] = make_uint4(hh[2], hh[3], hh[6], hh[7]);
        }
    }

    // ---- epilogue: transpose O^T -> O through reused LDS, coalesced store
    __syncthreads(); // everyone done with K/V buffers
    ushort* ot = SH + wave * (32 * 136); // per-wave 32 rows x 136 us
    uint* ot32 = (uint*)ot;
    {
        float inv = 1.0f / l_run;
        #pragma unroll
        for (int vt = 0; vt < 4; ++vt)
            #pragma unroll
            for (int g = 0; g < 4; ++g) {
                int base = l32 * 68 + vt * 16 + g * 4 + hi * 2;
                ot32[base]     = packbf(oa[vt][g * 4 + 0] * inv, oa[vt][g * 4 + 1] * inv);
                ot32[base + 1] = packbf(oa[vt][g * 4 + 2] * inv, oa[vt][g * 4 + 3] * inv);
            }
    }
    // same-wave LDS ordering: no barrier needed
    #pragma unroll
    for (int pass = 0; pass < 8; ++pass) {
        int row_in = pass * 4 + (lane >> 4);
        int col8 = (lane & 15) * 8;
        uint4 v = *(const uint4*)&ot[row_in * 136 + col8];
        int srow = qrow_base + row_in;
        *(uint4*)(o_ws + (((size_t)b * S_SZ + srow) * NH + h) * DK + col8) = v;
    }
}

// ============================================================
// Kernel 4b: out = o_ws @ W_O + b_O via MFMA (unchanged)
// ============================================================
__global__ __launch_bounds__(256) void out_gemm_mfma_kernel(
    const ushort* __restrict__ A,    // o_ws [8192][1024] bf16
    const ushort* __restrict__ BT,   // wot  [1024 n][1024 k] bf16
    const float* __restrict__ b_O, float* __restrict__ out)
{
    __shared__ __align__(16) ushort As[128 * 32];
    __shared__ __align__(16) ushort Bs[128 * 32];

    const int tid = threadIdx.x;
    const int wave = tid >> 6;
    const int lane = tid & 63;
    const int quad = lane >> 4;
    const int l16 = lane & 15;
    const int wr = wave >> 1, wc = wave & 1;

    const int n0 = blockIdx.x * 128;
    const int m0 = blockIdx.y * 128;

    const int lrow = lane >> 2;
    const int lseg = (lane & 3) * 8;

    floatx4 acc[4][4];
    #pragma unroll
    for (int mt = 0; mt < 4; ++mt)
        #pragma unroll
        for (int nt = 0; nt < 4; ++nt)
            acc[mt][nt] = (floatx4){0.f, 0.f, 0.f, 0.f};

    for (int k0 = 0; k0 < DM; k0 += 32) {
        __syncthreads();
        {
            const ushort* g0 = A + (size_t)(m0 + wave * 32 + lrow) * DM + k0 + lseg;
            glds16(g0, &As[(wave * 32) * 32]);
            const ushort* g1 = A + (size_t)(m0 + wave * 32 + 16 + lrow) * DM + k0 + lseg;
            glds16(g1, &As[(wave * 32 + 16) * 32]);
        }
        {
            const ushort* g0 = BT + (size_t)(n0 + wave * 32 + lrow) * DM + k0 + lseg;
            glds16(g0, &Bs[(wave * 32) * 32]);
            const ushort* g1 = BT + (size_t)(n0 + wave * 32 + 16 + lrow) * DM + k0 + lseg;
            glds16(g1, &Bs[(wave * 32 + 16) * 32]);
        }
        __syncthreads();

        short8 af[4], bf[4];
        #pragma unroll
        for (int mt = 0; mt < 4; ++mt)
            af[mt] = *(const short8*)&As[(wr * 64 + mt * 16 + l16) * 32 + quad * 8];
        #pragma unroll
        for (int nt = 0; nt < 4; ++nt)
            bf[nt] = *(const short8*)&Bs[(wc * 64 + nt * 16 + l16) * 32 + quad * 8];
        #pragma unroll
        for (int mt = 0; mt < 4; ++mt)
            #pragma unroll
            for (int nt = 0; nt < 4; ++nt)
                acc[mt][nt] = __builtin_amdgcn_mfma_f32_16x16x32_bf16(af[mt], bf[nt], acc[mt][nt], 0, 0, 0);
    }

    float bo[4];
    #pragma unroll
    for (int nt = 0; nt < 4; ++nt) bo[nt] = b_O[n0 + wc * 64 + nt * 16 + l16];

    #pragma unroll
    for (int mt = 0; mt < 4; ++mt) {
        #pragma unroll
        for (int r = 0; r < 4; ++r) {
            int row = m0 + wr * 64 + mt * 16 + quad * 4 + r;
            float* orow = out + (size_t)row * DM + n0 + wc * 64;
            #pragma unroll
            for (int nt = 0; nt < 4; ++nt)
                orow[nt * 16 + l16] = acc[mt][nt][r] + bo[nt];
        }
    }
}

// ============================================================
extern "C" void kernel_launch(void* const* d_in, const int* in_sizes, int n_in,
                              void* d_out, int out_size, void* d_ws, size_t ws_size,
                              hipStream_t stream) {
    (void)in_sizes; (void)n_in; (void)out_size; (void)ws_size;

    const float* h_t   = (const float*)d_in[0];
    const float* W_DQ  = (const float*)d_in[1];
    const float* b_DQ  = (const float*)d_in[2];
    const float* W_UQ  = (const float*)d_in[3];
    const float* b_UQ  = (const float*)d_in[4];
    const float* W_DKV = (const float*)d_in[5];
    const float* b_DKV = (const float*)d_in[6];
    const float* W_UK  = (const float*)d_in[7];
    const float* b_UK  = (const float*)d_in[8];
    const float* W_UV  = (const float*)d_in[9];
    const float* b_UV  = (const float*)d_in[10];
    const float* W_QR  = (const float*)d_in[11];
    const float* b_QR  = (const float*)d_in[12];
    const float* W_KR  = (const float*)d_in[13];
    const float* b_KR  = (const float*)d_in[14];
    const float* W_O   = (const float*)d_in[15];
    const float* b_O   = (const float*)d_in[16];

    ushort* cqbf  = (ushort*)d_ws;                      // [8192][32]
    ushort* ckvbf = cqbf + (size_t)T_TOK * DC;
    ushort* krbf  = ckvbf + (size_t)T_TOK * DC;
    ushort* wcat  = krbf + (size_t)T_TOK * DC;          // [3328][32]
    float*  bcat  = (float*)(wcat + (size_t)NCOL * DC); // [3328]
    ushort* wdcat = (ushort*)(bcat + NCOL);             // [96][1024]
    float*  bdcat = (float*)(wdcat + (size_t)96 * DM);  // [96]
    ushort* q_ws  = (ushort*)(bdcat + 96);
    ushort* k_ws  = q_ws + (size_t)B_SZ * NH * S_SZ * DQK;
    ushort* v_ws  = k_ws + (size_t)B_SZ * NH * S_SZ * DQK;
    ushort* o_ws  = v_ws + (size_t)B_SZ * NH * S_SZ * DK;
    ushort* wot   = o_ws + (size_t)T_TOK * DM;

    float* out = (float*)d_out;

    prep_kernel<<<1224, 256, 0, stream>>>(
        W_O, W_UQ, b_UQ, W_QR, b_QR, W_UK, b_UK, W_UV, b_UV,
        W_DQ, b_DQ, W_DKV, b_DKV, W_KR, b_KR,
        wot, wcat, bcat, wdcat, bdcat);

    latent_mfma_kernel<<<T_TOK / 32, 128, 0, stream>>>(
        h_t, wdcat, bdcat, cqbf, ckvbf, krbf);

    build_qkv_mfma_kernel<<<dim3(T_TOK / 64, 4), 256, 0, stream>>>(
        cqbf, ckvbf, krbf, wcat, bcat, q_ws, k_ws, v_ws);

    attn_mfma_kernel<<<512, 256, 0, stream>>>(
        q_ws, k_ws, v_ws, o_ws);

    out_gemm_mfma_kernel<<<dim3(DM / 128, T_TOK / 128), 256, 0, stream>>>(
        o_ws, wot, b_O, out);
}